// Round 13
// baseline (998.290 us; speedup 1.0000x reference)
//
#include <hip/hip_runtime.h>

// Bahdanau attention: B=32, T=512, S=1024, H=512, fp32.
// out = context [B,T,H] ++ attn_last [B,S]
// ws  = Q4 [B,T/4,H/4,4t,4h] ++ E4 [B,H/4,S,4] (both f32); Q = e^{2*Wsq},
// E = e^{2*Whe} (clamped exp2 in matmul epilogues). Softmax shift-invariance
// => score' = sum_h (-2 v_h)/(1 + Q*E); h-quads via reciprocal tree (14 VALU
// + 1 rcp / 4). Streams: q per-block -> LDS broadcast; v -> scalar K$;
// E per-lane -> vector. r13: nS=4 strip batching (LDS q-load 80%->40%, 4x E
// MLP) + perfectly len-balanced schedule: passN<nsw> bulk (nsw=NS/4 strips/
// wave, 4t) + passTail<R> (R=NS%4 strips, each wave does its own t) -> per-
// wave work = NS/8 pair-equivalents exactly, no barrier quantization.

constexpr int B = 32, T = 512, S = 1024, H = 512;
constexpr int TT = 4;  // timesteps per attn block
constexpr float C2LOG2E = 2.88539008177792681f;  // 2*log2(e)

typedef float vf4 __attribute__((ext_vector_type(4)));

#define DEVI __device__ __forceinline__

DEVI vf4 exp2clampv(vf4 x) {
  vf4 r;
#pragma unroll
  for (int i = 0; i < 4; ++i)
    r[i] = __builtin_amdgcn_exp2f(fminf(fmaxf(x[i], -15.f), 15.f));
  return r;
}

// C = exp2(clamp(scale * A[M][512] * W[512][512]^T)).
// TRANS=false: Q4 layout [b][tile][h4][i][j]. TRANS=true: E4 layout
// [b][o/4][s][4], m = b*S + s; fully-masked s-tiles skipped.
template <bool TRANS>
__global__ __launch_bounds__(256)
void matmul_nt_kernel(const float* __restrict__ A, const float* __restrict__ W,
                      float* __restrict__ Cout, float scale, const int* __restrict__ lens) {
  constexpr int K = H, N = H, BM = 64, BN = 64, BK = 16;
  __shared__ __align__(16) float As[BK][BM + 4];
  __shared__ __align__(16) float Bs[BK][BN + 4];
  const int nbx = N / BN;  // 8
  const int bx = blockIdx.x % nbx, by = blockIdx.x / nbx;
  const int row0 = by * BM, col0 = bx * BN;
  if (TRANS) {  // rows row0..row0+63 are one batch; skip if fully masked
    if ((row0 % S) >= lens[row0 / S]) return;
  }
  const int tid = threadIdx.x;
  const int tx = tid & 15, ty = tid >> 4;
  const int lr = tid >> 2, lk = (tid & 3) * 4;
  float acc[4][4] = {};
  for (int k0 = 0; k0 < K; k0 += BK) {
    float4 av = *(const float4*)&A[(size_t)(row0 + lr) * K + k0 + lk];
    float4 wv = *(const float4*)&W[(size_t)(col0 + lr) * K + k0 + lk];
    __syncthreads();
    As[lk + 0][lr] = av.x; As[lk + 1][lr] = av.y; As[lk + 2][lr] = av.z; As[lk + 3][lr] = av.w;
    Bs[lk + 0][lr] = wv.x; Bs[lk + 1][lr] = wv.y; Bs[lk + 2][lr] = wv.z; Bs[lk + 3][lr] = wv.w;
    __syncthreads();
#pragma unroll
    for (int k = 0; k < BK; ++k) {
      float4 a4 = *(const float4*)&As[k][ty * 4];
      float4 w4 = *(const float4*)&Bs[k][tx * 4];
      float a[4] = {a4.x, a4.y, a4.z, a4.w};
      float w[4] = {w4.x, w4.y, w4.z, w4.w};
#pragma unroll
      for (int i = 0; i < 4; ++i)
#pragma unroll
        for (int j = 0; j < 4; ++j) acc[i][j] = __builtin_fmaf(a[i], w[j], acc[i][j]);
    }
  }
  if (!TRANS) {
    // Q4[b][tile][h4][i][j]: b=row0/T, tile=(row0%T)/4+ty, h4=col0/4+tx
    const int bq = row0 / T;
    const int tile = ((row0 % T) >> 2) + ty;
    float* base = Cout + (size_t)bq * T * H + (size_t)tile * (4 * H) +
                  (size_t)((col0 >> 2) + tx) * 16;
#pragma unroll
    for (int i = 0; i < 4; ++i) {
      vf4 o = {acc[i][0] * scale, acc[i][1] * scale, acc[i][2] * scale, acc[i][3] * scale};
      *(vf4*)&base[i * 4] = exp2clampv(o);
    }
  } else {
    const int b = row0 / S;
    const int sl = (row0 % S) + ty * 4;
    // E4[b][h4][s][c]: h4 = col0/4 + tx
    float* base = Cout + (size_t)b * H * S + (size_t)((col0 >> 2) + tx) * (4 * S);
#pragma unroll
    for (int i = 0; i < 4; ++i) {
      vf4 o = {acc[i][0] * scale, acc[i][1] * scale, acc[i][2] * scale, acc[i][3] * scale};
      *(vf4*)&base[(size_t)(sl + i) * 4] = exp2clampv(o);
    }
  }
}

// acc += sum_{i<4} vv[i] / (1 + q[i]*e[i]) via single-rcp reciprocal tree.
DEVI void tree4(float& acc, vf4 q, vf4 vv, vf4 e) {
  float a0 = __builtin_fmaf(q[0], e[0], 1.0f);
  float a1 = __builtin_fmaf(q[1], e[1], 1.0f);
  float a2 = __builtin_fmaf(q[2], e[2], 1.0f);
  float a3 = __builtin_fmaf(q[3], e[3], 1.0f);
  float d01 = a0 * a1, d23 = a2 * a3;
  float n01 = __builtin_fmaf(vv[1], a0, vv[0] * a1);
  float n23 = __builtin_fmaf(vv[3], a2, vv[2] * a3);
  float d = d01 * d23;
  float n = __builtin_fmaf(n23, d01, n01 * d23);
  acc = __builtin_fmaf(n, __builtin_amdgcn_rcpf(d), acc);
}

// Bulk: NSIM strips (stride 4 strips = 256 s) x 4 t, lane = s within strip.
template <int NSIM>
DEVI void passN(const float (&s_q)[H / 4][16], const float* __restrict__ v,
                const float* __restrict__ e4b, float (&s_sc)[TT][S],
                int wv, int lane) {
  float acc[NSIM][TT];
#pragma unroll
  for (int r = 0; r < NSIM; ++r)
#pragma unroll
    for (int t = 0; t < TT; ++t) acc[r][t] = 0.f;
  const float* ep = e4b + (size_t)(wv * 64 + lane) * 4;
#pragma unroll 2
  for (int h4 = 0; h4 < H / 4; ++h4) {
    vf4 e[NSIM];
#pragma unroll
    for (int r = 0; r < NSIM; ++r)
      e[r] = *(const vf4*)(ep + (size_t)h4 * (S * 4) + r * 1024);
    vf4 vv = *(const vf4*)(v + h4 * 4);  // wave-uniform -> s_load
    vf4 q0 = *(const vf4*)&s_q[h4][0];
    vf4 q1 = *(const vf4*)&s_q[h4][4];
    vf4 q2 = *(const vf4*)&s_q[h4][8];
    vf4 q3 = *(const vf4*)&s_q[h4][12];
#pragma unroll
    for (int r = 0; r < NSIM; ++r) {
      tree4(acc[r][0], q0, vv, e[r]);
      tree4(acc[r][1], q1, vv, e[r]);
      tree4(acc[r][2], q2, vv, e[r]);
      tree4(acc[r][3], q3, vv, e[r]);
    }
  }
#pragma unroll
  for (int r = 0; r < NSIM; ++r) {
    const int s = (wv + 4 * r) * 64 + lane;
#pragma unroll
    for (int t = 0; t < TT; ++t) s_sc[t][s] = -2.0f * acc[r][t];
  }
}

// Tail: R consecutive strips, each wave computes ONLY its own t = wv.
template <int R>
DEVI void passTail(const float (&s_q)[H / 4][16], const float* __restrict__ v,
                   const float* __restrict__ e4b, float (&s_sc)[TT][S],
                   int kbase, int wv, int lane) {
  float acc[R];
#pragma unroll
  for (int r = 0; r < R; ++r) acc[r] = 0.f;
  const float* ep = e4b + (size_t)(kbase * 64 + lane) * 4;
#pragma unroll 2
  for (int h4 = 0; h4 < H / 4; ++h4) {
    vf4 q = *(const vf4*)&s_q[h4][wv * 4];  // wave-uniform LDS broadcast
    vf4 vv = *(const vf4*)(v + h4 * 4);
#pragma unroll
    for (int r = 0; r < R; ++r) {
      vf4 e = *(const vf4*)(ep + (size_t)h4 * (S * 4) + r * 256);
      tree4(acc[r], q, vv, e);
    }
  }
#pragma unroll
  for (int r = 0; r < R; ++r)
    s_sc[wv][(kbase + r) * 64 + lane] = -2.0f * acc[r];
}

// Fused: scores -> masked softmax -> context. One block = (b, 4 timesteps).
__global__ __launch_bounds__(256, 6)
void attn_fused_kernel(const float* __restrict__ wsq, const float* __restrict__ wheT,
                       const float* __restrict__ enc, const float* __restrict__ v,
                       const int* __restrict__ lens, float* __restrict__ out) {
  __shared__ __align__(16) float s_sc[TT][S];    // 16 KB: scores, then p in place
  __shared__ __align__(16) float s_q[H / 4][16]; // 8 KB : Q4 tile (broadcast reads)
  __shared__ float s_rs[TT];
  __shared__ long long s_w[32];
  __shared__ int s_bsel;

  const int tid = threadIdx.x;
  const int xcd = blockIdx.x & 7;     // dispatch round-robin heuristic
  const int j = blockIdx.x >> 3;      // 0..511
  const int slot = j >> 7;            // 0..3: which of this XCD's 4 batches
  const int tt = j & 127;             // 0..127 t-tile within batch

  // Runtime snake load-balance: rank batches by len (desc), XCD x gets ranks
  // {x, 15-x, 16+x, 31-x} -> balanced work, batch-major locality.
  if (tid < 32) s_w[tid] = ((long long)lens[tid] << 8) + tid;  // unique key
  __syncthreads();
  if (tid < 32) {
    long long wb = s_w[tid];
    int rank = 0;
#pragma unroll
    for (int b2 = 0; b2 < 32; ++b2) rank += (s_w[b2] > wb);
    int myrank = slot * 8 + ((slot & 1) ? (7 - xcd) : xcd);
    if (rank == myrank) s_bsel = tid;
  }
  __syncthreads();
  const int b = __builtin_amdgcn_readfirstlane(s_bsel);
  const int len = lens[b];

  {  // stage the Q4 tile (2048 floats, contiguous in global) into LDS
    const vf4* src = (const vf4*)(wsq + (size_t)b * T * H + (size_t)tt * (4 * H));
    vf4* dst = (vf4*)&s_q[0][0];
    dst[tid] = src[tid];
    dst[tid + 256] = src[tid + 256];
  }
  __syncthreads();

  // ---- Phase A: perfectly balanced strip schedule ----
  {
    const int wv = tid >> 6, lane = tid & 63;
    const int NS = (len + 63) >> 6;  // 1..16 strips
    const int nsw = NS >> 2;         // bulk strips per wave (0..4)
    const int R = NS & 3;            // tail strips (0..3)
    const float* e4b = wheT + (size_t)b * H * S;  // [h4][s][4]
    switch (nsw) {
      case 1: passN<1>(s_q, v, e4b, s_sc, wv, lane); break;
      case 2: passN<2>(s_q, v, e4b, s_sc, wv, lane); break;
      case 3: passN<3>(s_q, v, e4b, s_sc, wv, lane); break;
      case 4: passN<4>(s_q, v, e4b, s_sc, wv, lane); break;
      default: break;
    }
    switch (R) {
      case 1: passTail<1>(s_q, v, e4b, s_sc, nsw * 4, wv, lane); break;
      case 2: passTail<2>(s_q, v, e4b, s_sc, nsw * 4, wv, lane); break;
      case 3: passTail<3>(s_q, v, e4b, s_sc, nsw * 4, wv, lane); break;
      default: break;
    }
  }
  __syncthreads();

  // ---- Phase B: masked softmax; wave w handles row w ----
  {
    const int tr = tid >> 6, lane = tid & 63;
    float vals[S / 64], ps[S / 64];
    float m = -3.0e38f;
#pragma unroll
    for (int i = 0; i < S / 64; ++i) {
      int s = lane + 64 * i;
      vals[i] = s_sc[tr][s];
      if (s < len) m = fmaxf(m, vals[i]);
    }
#pragma unroll
    for (int o = 1; o < 64; o <<= 1) m = fmaxf(m, __shfl_xor(m, o, 64));
    float sum = 0.f;
#pragma unroll
    for (int i = 0; i < S / 64; ++i) {
      int s = lane + 64 * i;
      float p = (s < len) ? __builtin_amdgcn_exp2f((vals[i] - m) * 1.44269504088896341f) : 0.f;
      ps[i] = p;
      sum += p;
    }
#pragma unroll
    for (int o = 1; o < 64; o <<= 1) sum += __shfl_xor(sum, o, 64);
    float rs = 1.0f / sum;
#pragma unroll
    for (int i = 0; i < S / 64; ++i) s_sc[tr][lane + 64 * i] = ps[i];
    if (lane == 0) s_rs[tr] = rs;
    if (tt == T / TT - 1 && tr == TT - 1) {  // last timestep: attention weights
#pragma unroll
      for (int i = 0; i < S / 64; ++i)
        out[(size_t)B * T * H + (size_t)b * S + lane + 64 * i] = ps[i] * rs;
    }
  }
  __syncthreads();

  // ---- Phase C: ctx[t][h] = sum_{s<len} p[t][s] * enc[b][s][h]; wave = t ----
  {
    const int tg = tid >> 6, lane = tid & 63;
    const int h0 = lane * 4, h1 = 256 + lane * 4;
    float acc[8] = {};
    const float* encb = enc + (size_t)b * S * H;
    const int len4 = (len + 3) & ~3;  // p == 0 beyond len, safe to over-read
    for (int s0 = 0; s0 < len4; s0 += 4) {
      vf4 p4 = *(const vf4*)&s_sc[tg][s0];
#pragma unroll
      for (int kk = 0; kk < 4; ++kk) {
        const float* er = encb + (size_t)(s0 + kk) * H;
        float4 e0 = *(const float4*)(er + h0);
        float4 e1 = *(const float4*)(er + h1);
        float ev[8] = {e0.x, e0.y, e0.z, e0.w, e1.x, e1.y, e1.z, e1.w};
#pragma unroll
        for (int q = 0; q < 8; ++q) acc[q] = __builtin_fmaf(p4[kk], ev[q], acc[q]);
      }
    }
    const float rs = s_rs[tg];
    const size_t base = ((size_t)b * T + tt * TT + tg) * H;
    float4 o;
    o = make_float4(acc[0] * rs, acc[1] * rs, acc[2] * rs, acc[3] * rs);
    *(float4*)&out[base + h0] = o;
    o = make_float4(acc[4] * rs, acc[5] * rs, acc[6] * rs, acc[7] * rs);
    *(float4*)&out[base + h1] = o;
  }
}

extern "C" void kernel_launch(void* const* d_in, const int* in_sizes, int n_in,
                              void* d_out, int out_size, void* d_ws, size_t ws_size,
                              hipStream_t stream) {
  const float* query = (const float*)d_in[0];  // [B,T,H]
  const float* enc   = (const float*)d_in[1];  // [B,S,H]
  const int*   lens  = (const int*)d_in[2];    // [B]
  const float* Ws    = (const float*)d_in[3];  // [H,H]
  const float* Wh    = (const float*)d_in[4];  // [H,H]
  const float* v     = (const float*)d_in[5];  // [H]
  float* out = (float*)d_out;
  float* wsq  = (float*)d_ws;                  // Q4 [B,T/4,H/4,4,4]
  float* wheT = wsq + (size_t)B * T * H;       // E4 [B,H/4,S,4]

  matmul_nt_kernel<false><<<dim3((B * T / 64) * 8), 256, 0, stream>>>(query, Ws, wsq, C2LOG2E, nullptr);
  matmul_nt_kernel<true><<<dim3((B * S / 64) * 8), 256, 0, stream>>>(enc, Wh, wheT, C2LOG2E, lens);
  attn_fused_kernel<<<dim3(B * (T / TT)), 256, 0, stream>>>(wsq, wheT, enc, v, lens, out);
}

// Round 14
// 775.928 us; speedup vs baseline: 1.2866x; 1.2866x over previous
//
#include <hip/hip_runtime.h>

// Bahdanau attention: B=32, T=512, S=1024, H=512, fp32.
// out = context [B,T,H] ++ attn_last [B,S]
// ws  = Q4 [B,T/4,H/4,4t,4h] ++ E4 [B,H/4,S,4] (f32); Q = e^{2*Wsq},
// E = e^{2*Whe} (clamped exp2 in matmul epilogues). Softmax shift-invariance
// => score' = sum_h (-2 v_h)/(1 + Q*E); h-quads via single-rcp reciprocal
// tree. r14: TT=8 (halves E+enc L2 traffic, the measured floor), 3 blocks/CU,
// bulk(8t x nsw strips)+tail(2t x R strips) balanced schedule, both matmuls
// merged into one concurrent launch.

constexpr int B = 32, T = 512, S = 1024, H = 512;
constexpr int TT = 8;  // timesteps per attn block
constexpr float C2LOG2E = 2.88539008177792681f;  // 2*log2(e)
constexpr int QBLOCKS = (B * T / 64) * 8;  // 2048
constexpr int EBLOCKS = (B * S / 64) * 8;  // 4096

typedef float vf4 __attribute__((ext_vector_type(4)));

#define DEVI __device__ __forceinline__

DEVI vf4 exp2clampv(vf4 x) {
  vf4 r;
#pragma unroll
  for (int i = 0; i < 4; ++i)
    r[i] = __builtin_amdgcn_exp2f(fminf(fmaxf(x[i], -15.f), 15.f));
  return r;
}

// C = exp2(clamp(scale * A[M][512] * W[512][512]^T)).
// TRANS=false: Q4 layout [b][tile][h4][i][j]. TRANS=true: E4 layout
// [b][o/4][s][4], m = b*S + s; fully-masked s-tiles skipped.
template <bool TRANS>
DEVI void matmul_body(float (&As)[16][68], float (&Bs)[16][68], int blk,
                      const float* __restrict__ A, const float* __restrict__ W,
                      float* __restrict__ Cout, float scale, const int* __restrict__ lens,
                      int tid) {
  constexpr int K = H, BK = 16;
  const int bx = blk & 7, by = blk >> 3;
  const int row0 = by * 64, col0 = bx * 64;
  if (TRANS) {
    if ((row0 % S) >= lens[row0 / S]) return;
  }
  const int tx = tid & 15, ty = tid >> 4;
  const int lr = tid >> 2, lk = (tid & 3) * 4;
  float acc[4][4] = {};
  for (int k0 = 0; k0 < K; k0 += BK) {
    float4 av = *(const float4*)&A[(size_t)(row0 + lr) * K + k0 + lk];
    float4 wv = *(const float4*)&W[(size_t)(col0 + lr) * K + k0 + lk];
    __syncthreads();
    As[lk + 0][lr] = av.x; As[lk + 1][lr] = av.y; As[lk + 2][lr] = av.z; As[lk + 3][lr] = av.w;
    Bs[lk + 0][lr] = wv.x; Bs[lk + 1][lr] = wv.y; Bs[lk + 2][lr] = wv.z; Bs[lk + 3][lr] = wv.w;
    __syncthreads();
#pragma unroll
    for (int k = 0; k < BK; ++k) {
      float4 a4 = *(const float4*)&As[k][ty * 4];
      float4 w4 = *(const float4*)&Bs[k][tx * 4];
      float a[4] = {a4.x, a4.y, a4.z, a4.w};
      float w[4] = {w4.x, w4.y, w4.z, w4.w};
#pragma unroll
      for (int i = 0; i < 4; ++i)
#pragma unroll
        for (int j = 0; j < 4; ++j) acc[i][j] = __builtin_fmaf(a[i], w[j], acc[i][j]);
    }
  }
  if (!TRANS) {
    const int bq = row0 / T;
    const int tile = ((row0 % T) >> 2) + ty;
    float* base = Cout + (size_t)bq * T * H + (size_t)tile * (4 * H) +
                  (size_t)((col0 >> 2) + tx) * 16;
#pragma unroll
    for (int i = 0; i < 4; ++i) {
      vf4 o = {acc[i][0] * scale, acc[i][1] * scale, acc[i][2] * scale, acc[i][3] * scale};
      *(vf4*)&base[i * 4] = exp2clampv(o);
    }
  } else {
    const int b = row0 / S;
    const int sl = (row0 % S) + ty * 4;
    float* base = Cout + (size_t)b * H * S + (size_t)((col0 >> 2) + tx) * (4 * S);
#pragma unroll
    for (int i = 0; i < 4; ++i) {
      vf4 o = {acc[i][0] * scale, acc[i][1] * scale, acc[i][2] * scale, acc[i][3] * scale};
      *(vf4*)&base[(size_t)(sl + i) * 4] = exp2clampv(o);
    }
  }
}

__global__ __launch_bounds__(256)
void matmul_both_kernel(const float* __restrict__ query, const float* __restrict__ enc,
                        const float* __restrict__ Ws, const float* __restrict__ Wh,
                        float* __restrict__ wsq, float* __restrict__ e4,
                        const int* __restrict__ lens) {
  __shared__ __align__(16) float As[16][68];
  __shared__ __align__(16) float Bs[16][68];
  const int blk = blockIdx.x;
  if (blk < QBLOCKS)
    matmul_body<false>(As, Bs, blk, query, Ws, wsq, C2LOG2E, nullptr, threadIdx.x);
  else
    matmul_body<true>(As, Bs, blk - QBLOCKS, enc, Wh, e4, C2LOG2E, lens, threadIdx.x);
}

// acc += sum_{i<4} vv[i] / (1 + q[i]*e[i]) via single-rcp reciprocal tree.
DEVI void tree4(float& acc, vf4 q, vf4 vv, vf4 e) {
  float a0 = __builtin_fmaf(q[0], e[0], 1.0f);
  float a1 = __builtin_fmaf(q[1], e[1], 1.0f);
  float a2 = __builtin_fmaf(q[2], e[2], 1.0f);
  float a3 = __builtin_fmaf(q[3], e[3], 1.0f);
  float d01 = a0 * a1, d23 = a2 * a3;
  float n01 = __builtin_fmaf(vv[1], a0, vv[0] * a1);
  float n23 = __builtin_fmaf(vv[3], a2, vv[2] * a3);
  float d = d01 * d23;
  float n = __builtin_fmaf(n23, d01, n01 * d23);
  acc = __builtin_fmaf(n, __builtin_amdgcn_rcpf(d), acc);
}

// Bulk: NSIM strips (stride 4 strips) x 8 t. q vf4 for t: s_q[h4] flat vf4
// index (t>>2)*4 + (t&3).
template <int NSIM>
DEVI void passN8(const float (&s_q)[H / 4][32], const float* __restrict__ v,
                 const float* __restrict__ e4b, float (&s_sc)[TT][S],
                 int wv, int lane) {
  float acc[NSIM][TT];
#pragma unroll
  for (int r = 0; r < NSIM; ++r)
#pragma unroll
    for (int t = 0; t < TT; ++t) acc[r][t] = 0.f;
  const float* ep = e4b + (size_t)(wv * 64 + lane) * 4;
#pragma unroll 2
  for (int h4 = 0; h4 < H / 4; ++h4) {
    vf4 e[NSIM];
#pragma unroll
    for (int r = 0; r < NSIM; ++r)
      e[r] = *(const vf4*)(ep + (size_t)h4 * (S * 4) + r * 1024);
    vf4 vv = *(const vf4*)(v + h4 * 4);  // wave-uniform -> s_load, K$-hot
    vf4 qv[TT];
#pragma unroll
    for (int t = 0; t < TT; ++t)
      qv[t] = *(const vf4*)&s_q[h4][((t >> 2) * 4 + (t & 3)) * 4];
#pragma unroll
    for (int r = 0; r < NSIM; ++r)
#pragma unroll
      for (int t = 0; t < TT; ++t) tree4(acc[r][t], qv[t], vv, e[r]);
  }
#pragma unroll
  for (int r = 0; r < NSIM; ++r) {
    const int s = (wv + 4 * r) * 64 + lane;
#pragma unroll
    for (int t = 0; t < TT; ++t) s_sc[t][s] = -2.0f * acc[r][t];
  }
}

// Tail: R consecutive strips, wave computes rows {wv, wv+4} only.
template <int R>
DEVI void passTail8(const float (&s_q)[H / 4][32], const float* __restrict__ v,
                    const float* __restrict__ e4b, float (&s_sc)[TT][S],
                    int kbase, int wv, int lane) {
  float acc[R][2];
#pragma unroll
  for (int r = 0; r < R; ++r) { acc[r][0] = 0.f; acc[r][1] = 0.f; }
  const float* ep = e4b + (size_t)(kbase * 64 + lane) * 4;
#pragma unroll 2
  for (int h4 = 0; h4 < H / 4; ++h4) {
    vf4 q0 = *(const vf4*)&s_q[h4][wv * 4];         // t = wv (tile 0)
    vf4 q1 = *(const vf4*)&s_q[h4][16 + wv * 4];    // t = wv+4 (tile 1)
    vf4 vv = *(const vf4*)(v + h4 * 4);
#pragma unroll
    for (int r = 0; r < R; ++r) {
      vf4 e = *(const vf4*)(ep + (size_t)h4 * (S * 4) + r * 256);
      tree4(acc[r][0], q0, vv, e);
      tree4(acc[r][1], q1, vv, e);
    }
  }
#pragma unroll
  for (int r = 0; r < R; ++r) {
    s_sc[wv][(kbase + r) * 64 + lane] = -2.0f * acc[r][0];
    s_sc[wv + 4][(kbase + r) * 64 + lane] = -2.0f * acc[r][1];
  }
}

// Fused: scores -> masked softmax -> context. One block = (b, 8 timesteps).
__global__ __launch_bounds__(256, 3)
void attn_fused_kernel(const float* __restrict__ wsq, const float* __restrict__ wheT,
                       const float* __restrict__ enc, const float* __restrict__ v,
                       const int* __restrict__ lens, float* __restrict__ out) {
  __shared__ __align__(16) float s_sc[TT][S];    // 32 KB: scores, then p in place
  __shared__ __align__(16) float s_q[H / 4][32]; // 16 KB: Q for 8 t (broadcast)
  __shared__ float s_rs[TT];
  __shared__ long long s_w[32];
  __shared__ int s_bsel;

  const int tid = threadIdx.x;
  const int xcd = blockIdx.x & 7;     // dispatch round-robin heuristic
  const int j = blockIdx.x >> 3;      // 0..255
  const int slot = j >> 6;            // 0..3: which of this XCD's 4 batches
  const int tt = j & 63;              // 0..63 t-tile within batch

  // Runtime snake load-balance: rank batches by len (desc), XCD x gets ranks
  // {x, 15-x, 16+x, 31-x} -> balanced work, batch-major locality.
  if (tid < 32) s_w[tid] = ((long long)lens[tid] << 8) + tid;  // unique key
  __syncthreads();
  if (tid < 32) {
    long long wb = s_w[tid];
    int rank = 0;
#pragma unroll
    for (int b2 = 0; b2 < 32; ++b2) rank += (s_w[b2] > wb);
    int myrank = slot * 8 + ((slot & 1) ? (7 - xcd) : xcd);
    if (rank == myrank) s_bsel = tid;
  }
  __syncthreads();
  const int b = __builtin_amdgcn_readfirstlane(s_bsel);
  const int len = lens[b];

  {  // stage Q for 8 t (two consecutive Q4 tiles = 16 KB contiguous)
    const vf4* src = (const vf4*)(wsq + (size_t)b * T * H + (size_t)tt * (TT * H));
    vf4* dst = (vf4*)&s_q[0][0];
#pragma unroll
    for (int u = 0; u < 4; ++u) {
      int g = tid + u * 256;  // global vf4 idx: tile*512 + h4*4 + i
      int l = ((g >> 2) & 127) * 8 + (g >> 9) * 4 + (g & 3);
      dst[l] = src[g];
    }
  }
  __syncthreads();

  // ---- Phase A: balanced strip schedule (bulk 8t + tail 2t/wave) ----
  {
    const int wv = tid >> 6, lane = tid & 63;
    const int NS = (len + 63) >> 6;  // 1..16 strips
    const int nsw = NS >> 2;         // bulk strips per wave (0..4)
    const int R = NS & 3;            // tail strips (0..3)
    const float* e4b = wheT + (size_t)b * H * S;  // [h4][s][4]
    switch (nsw) {
      case 1: passN8<1>(s_q, v, e4b, s_sc, wv, lane); break;
      case 2: passN8<2>(s_q, v, e4b, s_sc, wv, lane); break;
      case 3: passN8<3>(s_q, v, e4b, s_sc, wv, lane); break;
      case 4: passN8<4>(s_q, v, e4b, s_sc, wv, lane); break;
      default: break;
    }
    switch (R) {
      case 1: passTail8<1>(s_q, v, e4b, s_sc, nsw * 4, wv, lane); break;
      case 2: passTail8<2>(s_q, v, e4b, s_sc, nsw * 4, wv, lane); break;
      case 3: passTail8<3>(s_q, v, e4b, s_sc, nsw * 4, wv, lane); break;
      default: break;
    }
  }
  __syncthreads();

  // ---- Phase B: masked softmax; wave w handles rows {w, w+4} ----
  {
    const int wv = tid >> 6, lane = tid & 63;
#pragma unroll
    for (int jj = 0; jj < 2; ++jj) {
      const int tr = wv + 4 * jj;
      float vals[S / 64], ps[S / 64];
      float m = -3.0e38f;
#pragma unroll
      for (int i = 0; i < S / 64; ++i) {
        int s = lane + 64 * i;
        vals[i] = s_sc[tr][s];
        if (s < len) m = fmaxf(m, vals[i]);
      }
#pragma unroll
      for (int o = 1; o < 64; o <<= 1) m = fmaxf(m, __shfl_xor(m, o, 64));
      float sum = 0.f;
#pragma unroll
      for (int i = 0; i < S / 64; ++i) {
        int s = lane + 64 * i;
        float p = (s < len) ? __builtin_amdgcn_exp2f((vals[i] - m) * 1.44269504088896341f) : 0.f;
        ps[i] = p;
        sum += p;
      }
#pragma unroll
      for (int o = 1; o < 64; o <<= 1) sum += __shfl_xor(sum, o, 64);
      float rs = 1.0f / sum;
#pragma unroll
      for (int i = 0; i < S / 64; ++i) s_sc[tr][lane + 64 * i] = ps[i];
      if (lane == 0) s_rs[tr] = rs;
      if (tt == T / TT - 1 && tr == TT - 1) {  // last timestep: attention weights
#pragma unroll
        for (int i = 0; i < S / 64; ++i)
          out[(size_t)B * T * H + (size_t)b * S + lane + 64 * i] = ps[i] * rs;
      }
    }
  }
  __syncthreads();

  // ---- Phase C: ctx; wave w does rows {w, w+4}, enc loads shared ----
  {
    const int wv = tid >> 6, lane = tid & 63;
    const int h0 = lane * 4, h1 = 256 + lane * 4;
    float acc0[8] = {}, acc1[8] = {};
    const float* encb = enc + (size_t)b * S * H;
    const int len4 = (len + 3) & ~3;  // p == 0 beyond len, safe to over-read
    for (int s0 = 0; s0 < len4; s0 += 4) {
      vf4 p4a = *(const vf4*)&s_sc[wv][s0];
      vf4 p4b = *(const vf4*)&s_sc[wv + 4][s0];
#pragma unroll
      for (int kk = 0; kk < 4; ++kk) {
        const float* er = encb + (size_t)(s0 + kk) * H;
        float4 e0 = *(const float4*)(er + h0);
        float4 e1 = *(const float4*)(er + h1);
        float ev[8] = {e0.x, e0.y, e0.z, e0.w, e1.x, e1.y, e1.z, e1.w};
#pragma unroll
        for (int q = 0; q < 8; ++q) {
          acc0[q] = __builtin_fmaf(p4a[kk], ev[q], acc0[q]);
          acc1[q] = __builtin_fmaf(p4b[kk], ev[q], acc1[q]);
        }
      }
    }
    const float rs0 = s_rs[wv], rs1 = s_rs[wv + 4];
    const size_t base0 = ((size_t)b * T + tt * TT + wv) * H;
    const size_t base1 = ((size_t)b * T + tt * TT + wv + 4) * H;
    float4 o;
    o = make_float4(acc0[0] * rs0, acc0[1] * rs0, acc0[2] * rs0, acc0[3] * rs0);
    *(float4*)&out[base0 + h0] = o;
    o = make_float4(acc0[4] * rs0, acc0[5] * rs0, acc0[6] * rs0, acc0[7] * rs0);
    *(float4*)&out[base0 + h1] = o;
    o = make_float4(acc1[0] * rs1, acc1[1] * rs1, acc1[2] * rs1, acc1[3] * rs1);
    *(float4*)&out[base1 + h0] = o;
    o = make_float4(acc1[4] * rs1, acc1[5] * rs1, acc1[6] * rs1, acc1[7] * rs1);
    *(float4*)&out[base1 + h1] = o;
  }
}

extern "C" void kernel_launch(void* const* d_in, const int* in_sizes, int n_in,
                              void* d_out, int out_size, void* d_ws, size_t ws_size,
                              hipStream_t stream) {
  const float* query = (const float*)d_in[0];  // [B,T,H]
  const float* enc   = (const float*)d_in[1];  // [B,S,H]
  const int*   lens  = (const int*)d_in[2];    // [B]
  const float* Ws    = (const float*)d_in[3];  // [H,H]
  const float* Wh    = (const float*)d_in[4];  // [H,H]
  const float* v     = (const float*)d_in[5];  // [H]
  float* out = (float*)d_out;
  float* wsq  = (float*)d_ws;                  // Q4 [B,T/4,H/4,4,4]
  float* wheT = wsq + (size_t)B * T * H;       // E4 [B,H/4,S,4]

  matmul_both_kernel<<<dim3(QBLOCKS + EBLOCKS), 256, 0, stream>>>(query, enc, Ws, Wh, wsq, wheT, lens);
  attn_fused_kernel<<<dim3(B * (T / TT)), 256, 0, stream>>>(wsq, wheT, enc, v, lens, out);
}

// Round 15
// 735.563 us; speedup vs baseline: 1.3572x; 1.0549x over previous
//
#include <hip/hip_runtime.h>

// Bahdanau attention: B=32, T=512, S=1024, H=512, fp32.
// out = context [B,T,H] ++ attn_last [B,S]
// ws  = Q4 [B,T/4,H/4,4t,4h] ++ E4 [B,H/4,S,4] (f32); Q = e^{2*Wsq},
// E = e^{2*Whe} (clamped exp2 in matmul epilogues). Softmax shift-invariance
// => score' = sum_h (-2 v_h)/(1 + Q*E); h-quads via single-rcp reciprocal
// tree. r15: TT=16 (halves E+enc L2/L3 stream again, the r14-confirmed
// floor) with LDS held at ~49KB via bf16 s_q (16KB) + bf16 s_sc (32KB) ->
// still 3 blocks/CU. Balanced bulk(16t x nsw strips)+tail(4t x R strips).

constexpr int B = 32, T = 512, S = 1024, H = 512;
constexpr int TT = 16;  // timesteps per attn block
constexpr float C2LOG2E = 2.88539008177792681f;  // 2*log2(e)
constexpr int QBLOCKS = (B * T / 64) * 8;  // 2048
constexpr int EBLOCKS = (B * S / 64) * 8;  // 4096

typedef float vf4 __attribute__((ext_vector_type(4)));
typedef unsigned short ushort_t;

#define DEVI __device__ __forceinline__

DEVI vf4 exp2clampv(vf4 x) {
  vf4 r;
#pragma unroll
  for (int i = 0; i < 4; ++i)
    r[i] = __builtin_amdgcn_exp2f(fminf(fmaxf(x[i], -15.f), 15.f));
  return r;
}

DEVI unsigned pack_bf16(float a, float b) {  // round-half-up; |x| << 2^127 so safe
  unsigned ua = __builtin_bit_cast(unsigned, a) + 0x8000u;
  unsigned ub = __builtin_bit_cast(unsigned, b) + 0x8000u;
  return (ub & 0xffff0000u) | (ua >> 16);
}
DEVI ushort_t to_bf16u(float x) {
  return (ushort_t)((__builtin_bit_cast(unsigned, x) + 0x8000u) >> 16);
}
DEVI float bf_lo(unsigned d) { return __builtin_bit_cast(float, d << 16); }
DEVI float bf_hi(unsigned d) { return __builtin_bit_cast(float, d & 0xffff0000u); }
DEVI float bf_one(ushort_t u) { return __builtin_bit_cast(float, (unsigned)u << 16); }

// C = exp2(clamp(scale * A[M][512] * W[512][512]^T)).
// TRANS=false: Q4 layout [b][tile][h4][i][j]. TRANS=true: E4 layout
// [b][o/4][s][4], m = b*S + s; fully-masked s-tiles skipped.
template <bool TRANS>
DEVI void matmul_body(float (&As)[16][68], float (&Bs)[16][68], int blk,
                      const float* __restrict__ A, const float* __restrict__ W,
                      float* __restrict__ Cout, float scale, const int* __restrict__ lens,
                      int tid) {
  constexpr int K = H, BK = 16;
  const int bx = blk & 7, by = blk >> 3;
  const int row0 = by * 64, col0 = bx * 64;
  if (TRANS) {
    if ((row0 % S) >= lens[row0 / S]) return;
  }
  const int tx = tid & 15, ty = tid >> 4;
  const int lr = tid >> 2, lk = (tid & 3) * 4;
  float acc[4][4] = {};
  for (int k0 = 0; k0 < K; k0 += BK) {
    float4 av = *(const float4*)&A[(size_t)(row0 + lr) * K + k0 + lk];
    float4 wv = *(const float4*)&W[(size_t)(col0 + lr) * K + k0 + lk];
    __syncthreads();
    As[lk + 0][lr] = av.x; As[lk + 1][lr] = av.y; As[lk + 2][lr] = av.z; As[lk + 3][lr] = av.w;
    Bs[lk + 0][lr] = wv.x; Bs[lk + 1][lr] = wv.y; Bs[lk + 2][lr] = wv.z; Bs[lk + 3][lr] = wv.w;
    __syncthreads();
#pragma unroll
    for (int k = 0; k < BK; ++k) {
      float4 a4 = *(const float4*)&As[k][ty * 4];
      float4 w4 = *(const float4*)&Bs[k][tx * 4];
      float a[4] = {a4.x, a4.y, a4.z, a4.w};
      float w[4] = {w4.x, w4.y, w4.z, w4.w};
#pragma unroll
      for (int i = 0; i < 4; ++i)
#pragma unroll
        for (int j = 0; j < 4; ++j) acc[i][j] = __builtin_fmaf(a[i], w[j], acc[i][j]);
    }
  }
  if (!TRANS) {
    const int bq = row0 / T;
    const int tile = ((row0 % T) >> 2) + ty;
    float* base = Cout + (size_t)bq * T * H + (size_t)tile * (4 * H) +
                  (size_t)((col0 >> 2) + tx) * 16;
#pragma unroll
    for (int i = 0; i < 4; ++i) {
      vf4 o = {acc[i][0] * scale, acc[i][1] * scale, acc[i][2] * scale, acc[i][3] * scale};
      *(vf4*)&base[i * 4] = exp2clampv(o);
    }
  } else {
    const int b = row0 / S;
    const int sl = (row0 % S) + ty * 4;
    float* base = Cout + (size_t)b * H * S + (size_t)((col0 >> 2) + tx) * (4 * S);
#pragma unroll
    for (int i = 0; i < 4; ++i) {
      vf4 o = {acc[i][0] * scale, acc[i][1] * scale, acc[i][2] * scale, acc[i][3] * scale};
      *(vf4*)&base[(size_t)(sl + i) * 4] = exp2clampv(o);
    }
  }
}

__global__ __launch_bounds__(256)
void matmul_both_kernel(const float* __restrict__ query, const float* __restrict__ enc,
                        const float* __restrict__ Ws, const float* __restrict__ Wh,
                        float* __restrict__ wsq, float* __restrict__ e4,
                        const int* __restrict__ lens) {
  __shared__ __align__(16) float As[16][68];
  __shared__ __align__(16) float Bs[16][68];
  const int blk = blockIdx.x;
  if (blk < QBLOCKS)
    matmul_body<false>(As, Bs, blk, query, Ws, wsq, C2LOG2E, nullptr, threadIdx.x);
  else
    matmul_body<true>(As, Bs, blk - QBLOCKS, enc, Wh, e4, C2LOG2E, lens, threadIdx.x);
}

// acc += sum_{i<4} vv[i] / (1 + q[i]*e[i]) via single-rcp reciprocal tree.
DEVI void tree4(float& acc, vf4 q, vf4 vv, vf4 e) {
  float a0 = __builtin_fmaf(q[0], e[0], 1.0f);
  float a1 = __builtin_fmaf(q[1], e[1], 1.0f);
  float a2 = __builtin_fmaf(q[2], e[2], 1.0f);
  float a3 = __builtin_fmaf(q[3], e[3], 1.0f);
  float d01 = a0 * a1, d23 = a2 * a3;
  float n01 = __builtin_fmaf(vv[1], a0, vv[0] * a1);
  float n23 = __builtin_fmaf(vv[3], a2, vv[2] * a3);
  float d = d01 * d23;
  float n = __builtin_fmaf(n23, d01, n01 * d23);
  acc = __builtin_fmaf(n, __builtin_amdgcn_rcpf(d), acc);
}

DEVI vf4 qload(const ushort_t (&s_q16)[H / 4][64], int h4, int t) {
  uint2 qu = *(const uint2*)&s_q16[h4][t * 4];
  vf4 q = {bf_lo(qu.x), bf_hi(qu.x), bf_lo(qu.y), bf_hi(qu.y)};
  return q;
}

// Bulk: NSIM strips (stride 4 strips) x 16 t.
template <int NSIM>
DEVI void passN16(const ushort_t (&s_q16)[H / 4][64], const float* __restrict__ v,
                  const float* __restrict__ e4b, ushort_t (&s_sc16)[TT][S],
                  int wv, int lane) {
  float acc[NSIM][TT];
#pragma unroll
  for (int r = 0; r < NSIM; ++r)
#pragma unroll
    for (int t = 0; t < TT; ++t) acc[r][t] = 0.f;
  const float* ep = e4b + (size_t)(wv * 64 + lane) * 4;
  for (int h4 = 0; h4 < H / 4; ++h4) {
    vf4 e[NSIM];
#pragma unroll
    for (int r = 0; r < NSIM; ++r)
      e[r] = *(const vf4*)(ep + (size_t)h4 * (S * 4) + r * 1024);
    vf4 vv = *(const vf4*)(v + h4 * 4);  // wave-uniform -> s_load, K$-hot
#pragma unroll
    for (int t = 0; t < TT; ++t) {
      vf4 q = qload(s_q16, h4, t);
#pragma unroll
      for (int r = 0; r < NSIM; ++r) tree4(acc[r][t], q, vv, e[r]);
    }
  }
#pragma unroll
  for (int r = 0; r < NSIM; ++r) {
    const int s = (wv + 4 * r) * 64 + lane;
#pragma unroll
    for (int t = 0; t < TT; ++t) s_sc16[t][s] = to_bf16u(-2.0f * acc[r][t]);
  }
}

// Tail: R consecutive strips, wave computes rows {wv, wv+4, wv+8, wv+12}.
template <int R>
DEVI void passTail16(const ushort_t (&s_q16)[H / 4][64], const float* __restrict__ v,
                     const float* __restrict__ e4b, ushort_t (&s_sc16)[TT][S],
                     int kbase, int wv, int lane) {
  float acc[R][4];
#pragma unroll
  for (int r = 0; r < R; ++r)
#pragma unroll
    for (int jj = 0; jj < 4; ++jj) acc[r][jj] = 0.f;
  const float* ep = e4b + (size_t)(kbase * 64 + lane) * 4;
  for (int h4 = 0; h4 < H / 4; ++h4) {
    vf4 vv = *(const vf4*)(v + h4 * 4);
    vf4 e[R];
#pragma unroll
    for (int r = 0; r < R; ++r)
      e[r] = *(const vf4*)(ep + (size_t)h4 * (S * 4) + r * 256);
#pragma unroll
    for (int jj = 0; jj < 4; ++jj) {
      vf4 q = qload(s_q16, h4, wv + 4 * jj);
#pragma unroll
      for (int r = 0; r < R; ++r) tree4(acc[r][jj], q, vv, e[r]);
    }
  }
#pragma unroll
  for (int r = 0; r < R; ++r)
#pragma unroll
    for (int jj = 0; jj < 4; ++jj)
      s_sc16[wv + 4 * jj][(kbase + r) * 64 + lane] = to_bf16u(-2.0f * acc[r][jj]);
}

// Fused: scores -> masked softmax -> context. One block = (b, 16 timesteps).
__global__ __launch_bounds__(256, 3)
void attn_fused_kernel(const float* __restrict__ wsq, const float* __restrict__ wheT,
                       const float* __restrict__ enc, const float* __restrict__ v,
                       const int* __restrict__ lens, float* __restrict__ out) {
  __shared__ __align__(16) ushort_t s_sc16[TT][S];     // 32 KB bf16 scores/p
  __shared__ __align__(16) ushort_t s_q16[H / 4][64];  // 16 KB bf16 Q (broadcast)
  __shared__ float s_rs[TT];
  __shared__ long long s_w[32];
  __shared__ int s_bsel;

  const int tid = threadIdx.x;
  const int xcd = blockIdx.x & 7;     // dispatch round-robin heuristic
  const int j = blockIdx.x >> 3;      // 0..127
  const int slot = j >> 5;            // 0..3: which of this XCD's 4 batches
  const int tt = j & 31;              // 0..31 t-tile within batch

  // Runtime snake load-balance: rank batches by len (desc), XCD x gets ranks
  // {x, 15-x, 16+x, 31-x} -> balanced work, batch-major locality.
  if (tid < 32) s_w[tid] = ((long long)lens[tid] << 8) + tid;  // unique key
  __syncthreads();
  if (tid < 32) {
    long long wb = s_w[tid];
    int rank = 0;
#pragma unroll
    for (int b2 = 0; b2 < 32; ++b2) rank += (s_w[b2] > wb);
    int myrank = slot * 8 + ((slot & 1) ? (7 - xcd) : xcd);
    if (rank == myrank) s_bsel = tid;
  }
  __syncthreads();
  const int b = __builtin_amdgcn_readfirstlane(s_bsel);
  const int len = lens[b];

  {  // stage Q for 16 t (4 consecutive Q4 tiles = 8192 floats) as bf16
    const vf4* src = (const vf4*)(wsq + (size_t)b * T * H + (size_t)tt * (TT * H));
    uint2* dst = (uint2*)&s_q16[0][0];
#pragma unroll
    for (int u = 0; u < 8; ++u) {
      int g = tid + u * 256;            // vf4 index 0..2047
      vf4 qv = src[g];
      int tile = g >> 9, rem = g & 511;
      int h4 = rem >> 2, i = rem & 3;
      uint2 pk = make_uint2(pack_bf16(qv[0], qv[1]), pack_bf16(qv[2], qv[3]));
      dst[h4 * 16 + tile * 4 + i] = pk;
    }
  }
  __syncthreads();

  // ---- Phase A: balanced strip schedule (bulk 16t + tail 4t/wave) ----
  {
    const int wv = tid >> 6, lane = tid & 63;
    const int NS = (len + 63) >> 6;  // 1..16 strips
    const int nsw = NS >> 2;         // bulk strips per wave (0..4)
    const int R = NS & 3;            // tail strips (0..3)
    const float* e4b = wheT + (size_t)b * H * S;  // [h4][s][4]
    switch (nsw) {
      case 1: passN16<1>(s_q16, v, e4b, s_sc16, wv, lane); break;
      case 2: passN16<2>(s_q16, v, e4b, s_sc16, wv, lane); break;
      case 3: passN16<3>(s_q16, v, e4b, s_sc16, wv, lane); break;
      case 4: passN16<4>(s_q16, v, e4b, s_sc16, wv, lane); break;
      default: break;
    }
    switch (R) {
      case 1: passTail16<1>(s_q16, v, e4b, s_sc16, nsw * 4, wv, lane); break;
      case 2: passTail16<2>(s_q16, v, e4b, s_sc16, nsw * 4, wv, lane); break;
      case 3: passTail16<3>(s_q16, v, e4b, s_sc16, nsw * 4, wv, lane); break;
      default: break;
    }
  }
  __syncthreads();

  // ---- Phase B: masked softmax; wave w handles rows {w, w+4, w+8, w+12} ----
  {
    const int wv = tid >> 6, lane = tid & 63;
#pragma unroll
    for (int jj = 0; jj < 4; ++jj) {
      const int tr = wv + 4 * jj;
      float vals[S / 64], ps[S / 64];
      float m = -3.0e38f;
#pragma unroll
      for (int i = 0; i < S / 64; ++i) {
        int s = lane + 64 * i;
        vals[i] = bf_one(s_sc16[tr][s]);
        if (s < len) m = fmaxf(m, vals[i]);
      }
#pragma unroll
      for (int o = 1; o < 64; o <<= 1) m = fmaxf(m, __shfl_xor(m, o, 64));
      float sum = 0.f;
#pragma unroll
      for (int i = 0; i < S / 64; ++i) {
        int s = lane + 64 * i;
        float p = (s < len) ? __builtin_amdgcn_exp2f((vals[i] - m) * 1.44269504088896341f) : 0.f;
        ps[i] = p;
        sum += p;
      }
#pragma unroll
      for (int o = 1; o < 64; o <<= 1) sum += __shfl_xor(sum, o, 64);
      float rs = 1.0f / sum;
#pragma unroll
      for (int i = 0; i < S / 64; ++i) s_sc16[tr][lane + 64 * i] = to_bf16u(ps[i]);
      if (lane == 0) s_rs[tr] = rs;
      if (tt == T / TT - 1 && tr == TT - 1) {  // last timestep: attention weights
#pragma unroll
        for (int i = 0; i < S / 64; ++i)
          out[(size_t)B * T * H + (size_t)b * S + lane + 64 * i] = ps[i] * rs;
      }
    }
  }
  __syncthreads();

  // ---- Phase C: ctx; wave w does rows {w,w+4,w+8,w+12}, enc loads shared ----
  {
    const int wv = tid >> 6, lane = tid & 63;
    const int h0 = lane * 4, h1 = 256 + lane * 4;
    float acc[4][8] = {};
    const float* encb = enc + (size_t)b * S * H;
    const int len4 = (len + 3) & ~3;  // p == 0 beyond len, safe to over-read
    for (int s0 = 0; s0 < len4; s0 += 4) {
      vf4 pr[4];
#pragma unroll
      for (int jj = 0; jj < 4; ++jj) {
        uint2 pu = *(const uint2*)&s_sc16[wv + 4 * jj][s0];
        pr[jj] = (vf4){bf_lo(pu.x), bf_hi(pu.x), bf_lo(pu.y), bf_hi(pu.y)};
      }
#pragma unroll
      for (int kk = 0; kk < 4; ++kk) {
        const float* er = encb + (size_t)(s0 + kk) * H;
        float4 e0 = *(const float4*)(er + h0);
        float4 e1 = *(const float4*)(er + h1);
        float ev[8] = {e0.x, e0.y, e0.z, e0.w, e1.x, e1.y, e1.z, e1.w};
#pragma unroll
        for (int jj = 0; jj < 4; ++jj)
#pragma unroll
          for (int q = 0; q < 8; ++q)
            acc[jj][q] = __builtin_fmaf(pr[jj][kk], ev[q], acc[jj][q]);
      }
    }
#pragma unroll
    for (int jj = 0; jj < 4; ++jj) {
      const int tr = wv + 4 * jj;
      const float rs = s_rs[tr];
      const size_t base = ((size_t)b * T + tt * TT + tr) * H;
      float4 o;
      o = make_float4(acc[jj][0] * rs, acc[jj][1] * rs, acc[jj][2] * rs, acc[jj][3] * rs);
      *(float4*)&out[base + h0] = o;
      o = make_float4(acc[jj][4] * rs, acc[jj][5] * rs, acc[jj][6] * rs, acc[jj][7] * rs);
      *(float4*)&out[base + h1] = o;
    }
  }
}

extern "C" void kernel_launch(void* const* d_in, const int* in_sizes, int n_in,
                              void* d_out, int out_size, void* d_ws, size_t ws_size,
                              hipStream_t stream) {
  const float* query = (const float*)d_in[0];  // [B,T,H]
  const float* enc   = (const float*)d_in[1];  // [B,S,H]
  const int*   lens  = (const int*)d_in[2];    // [B]
  const float* Ws    = (const float*)d_in[3];  // [H,H]
  const float* Wh    = (const float*)d_in[4];  // [H,H]
  const float* v     = (const float*)d_in[5];  // [H]
  float* out = (float*)d_out;
  float* wsq  = (float*)d_ws;                  // Q4 [B,T/4,H/4,4,4]
  float* wheT = wsq + (size_t)B * T * H;       // E4 [B,H/4,S,4]

  matmul_both_kernel<<<dim3(QBLOCKS + EBLOCKS), 256, 0, stream>>>(query, enc, Ws, Wh, wsq, wheT, lens);
  attn_fused_kernel<<<dim3(B * (T / TT)), 256, 0, stream>>>(wsq, wheT, enc, v, lens, out);
}

// Round 16
// 563.703 us; speedup vs baseline: 1.7709x; 1.3049x over previous
//
#include <hip/hip_runtime.h>

// Bahdanau attention: B=32, T=512, S=1024, H=512, fp32.
// out = context [B,T,H] ++ attn_last [B,S]
// ws  = Q4 [B,T/4,H/4,4t,4h] ++ E4 [B,H/4,S,4] (f32); Q = e^{2*Wsq},
// E = e^{2*Whe}. r16: matmuls moved to bf16 MFMA (16x16x32), 128x128 tile,
// BK=64, f32->bf16 cvt during LDS staging; epilogue = exp2(clamp(scale*acc))
// scattered into the SAME Q4/E4 layouts as r15 -> attn kernel unchanged.
// Attn (r15): TT=16, bf16 s_q/s_sc, balanced bulk+tail strip schedule,
// score' = sum_h (-2 v_h)/(1+Q*E) via single-rcp reciprocal tree.

constexpr int B = 32, T = 512, S = 1024, H = 512;
constexpr int TT = 16;  // timesteps per attn block
constexpr float C2LOG2E = 2.88539008177792681f;  // 2*log2(e)

typedef float vf4 __attribute__((ext_vector_type(4)));
typedef float f32x4 __attribute__((ext_vector_type(4)));
typedef short bf16x8 __attribute__((ext_vector_type(8)));
typedef unsigned short ushort_t;

#define DEVI __device__ __forceinline__

DEVI unsigned pack_bf16(float a, float b) {  // round-half-up; safe (no inf inputs)
  unsigned ua = __builtin_bit_cast(unsigned, a) + 0x8000u;
  unsigned ub = __builtin_bit_cast(unsigned, b) + 0x8000u;
  return (ub & 0xffff0000u) | (ua >> 16);
}
DEVI ushort_t to_bf16u(float x) {
  return (ushort_t)((__builtin_bit_cast(unsigned, x) + 0x8000u) >> 16);
}
DEVI float bf_lo(unsigned d) { return __builtin_bit_cast(float, d << 16); }
DEVI float bf_hi(unsigned d) { return __builtin_bit_cast(float, d & 0xffff0000u); }
DEVI float bf_one(ushort_t u) { return __builtin_bit_cast(float, (unsigned)u << 16); }
DEVI float exp2c(float x) {
  return __builtin_amdgcn_exp2f(fminf(fmaxf(x, -15.f), 15.f));
}

// ---- MFMA matmul: Cout = exp2(clamp(scale * A[M,512] * W[512,512]^T)) ----
// 128x128 tile, BK=64, 4 waves of 64x64 (4x4 16x16x32 fragments).
// isE=false -> Q4 layout; isE=true -> E4 layout, masked 128-row tiles skipped.
constexpr int QBLK = (B * T / 128) * 4;  // 512
constexpr int EBLK = (B * S / 128) * 4;  // 1024

__global__ __launch_bounds__(256)
void mfma_matmul_kernel(const float* __restrict__ query, const float* __restrict__ enc,
                        const float* __restrict__ Ws, const float* __restrict__ Wh,
                        float* __restrict__ q4, float* __restrict__ e4,
                        const int* __restrict__ lens) {
  __shared__ short As[128][72];  // bf16 A-tile chunk [m][k], +8 pad
  __shared__ short Bs[128][72];  // bf16 W-tile chunk [n][k], +8 pad
  const int tid = threadIdx.x;
  int blk = blockIdx.x;
  const bool isE = blk >= QBLK;
  if (isE) blk -= QBLK;
  const int bx = blk & 3, by = blk >> 2;
  const int row0 = by * 128, col0 = bx * 128;
  const float* A = isE ? enc : query;
  const float* W = isE ? Wh : Ws;
  if (isE && (row0 % S) >= lens[row0 / S]) return;  // fully-masked s-tile

  const int lr = tid >> 4;        // 0..15 (row group for staging)
  const int lc = (tid & 15) * 4;  // 0..60 (k cols for staging)
  const int lane = tid & 63, wv = tid >> 6;
  const int wm = (wv >> 1) * 64, wn = (wv & 1) * 64;
  const int lrow = lane & 15, lkg = (lane >> 4) * 8;

  f32x4 acc[4][4] = {};
  for (int k0 = 0; k0 < H; k0 += 64) {
    __syncthreads();
#pragma unroll
    for (int u = 0; u < 8; ++u) {
      int r = lr + u * 16;
      float4 av = *(const float4*)&A[(size_t)(row0 + r) * H + k0 + lc];
      *(uint2*)&As[r][lc] = make_uint2(pack_bf16(av.x, av.y), pack_bf16(av.z, av.w));
      float4 wv4 = *(const float4*)&W[(size_t)(col0 + r) * H + k0 + lc];
      *(uint2*)&Bs[r][lc] = make_uint2(pack_bf16(wv4.x, wv4.y), pack_bf16(wv4.z, wv4.w));
    }
    __syncthreads();
#pragma unroll
    for (int ks = 0; ks < 64; ks += 32) {
      bf16x8 af[4], bfr[4];
#pragma unroll
      for (int i = 0; i < 4; ++i) {
        af[i] = *(const bf16x8*)&As[wm + i * 16 + lrow][ks + lkg];
        bfr[i] = *(const bf16x8*)&Bs[wn + i * 16 + lrow][ks + lkg];
      }
#pragma unroll
      for (int mt = 0; mt < 4; ++mt)
#pragma unroll
        for (int nt = 0; nt < 4; ++nt)
          acc[mt][nt] = __builtin_amdgcn_mfma_f32_16x16x32_bf16(
              af[mt], bfr[nt], acc[mt][nt], 0, 0, 0);
    }
  }

  // Epilogue: C frag layout col=lane&15, row=(lane>>4)*4+reg (m89-verified).
  const int crow = (lane >> 4) * 4, ccol = lane & 15;
  if (!isE) {
    const int b = row0 / T;
#pragma unroll
    for (int mt = 0; mt < 4; ++mt) {
      const int m = (row0 % T) + wm + mt * 16 + crow;  // multiple of 4
      const int tile_t = m >> 2;
#pragma unroll
      for (int nt = 0; nt < 4; ++nt) {
        const int n = col0 + wn + nt * 16 + ccol;
        float* base = q4 + (size_t)b * T * H + (size_t)tile_t * (4 * H) +
                      (n >> 2) * 16 + (n & 3);
        f32x4 a = acc[mt][nt];
#pragma unroll
        for (int reg = 0; reg < 4; ++reg) base[reg * 4] = exp2c(C2LOG2E * a[reg]);
      }
    }
  } else {
    const int b = row0 / S;
#pragma unroll
    for (int mt = 0; mt < 4; ++mt) {
      const int s0 = (row0 % S) + wm + mt * 16 + crow;
#pragma unroll
      for (int nt = 0; nt < 4; ++nt) {
        const int n = col0 + wn + nt * 16 + ccol;
        float* base = e4 + (size_t)b * H * S + (size_t)(n >> 2) * (4 * S) +
                      (size_t)s0 * 4 + (n & 3);
        f32x4 a = acc[mt][nt];
#pragma unroll
        for (int reg = 0; reg < 4; ++reg) base[reg * 4] = exp2c(C2LOG2E * a[reg]);
      }
    }
  }
}

// acc += sum_{i<4} vv[i] / (1 + q[i]*e[i]) via single-rcp reciprocal tree.
DEVI void tree4(float& acc, vf4 q, vf4 vv, vf4 e) {
  float a0 = __builtin_fmaf(q[0], e[0], 1.0f);
  float a1 = __builtin_fmaf(q[1], e[1], 1.0f);
  float a2 = __builtin_fmaf(q[2], e[2], 1.0f);
  float a3 = __builtin_fmaf(q[3], e[3], 1.0f);
  float d01 = a0 * a1, d23 = a2 * a3;
  float n01 = __builtin_fmaf(vv[1], a0, vv[0] * a1);
  float n23 = __builtin_fmaf(vv[3], a2, vv[2] * a3);
  float d = d01 * d23;
  float n = __builtin_fmaf(n23, d01, n01 * d23);
  acc = __builtin_fmaf(n, __builtin_amdgcn_rcpf(d), acc);
}

DEVI vf4 qload(const ushort_t (&s_q16)[H / 4][64], int h4, int t) {
  uint2 qu = *(const uint2*)&s_q16[h4][t * 4];
  vf4 q = {bf_lo(qu.x), bf_hi(qu.x), bf_lo(qu.y), bf_hi(qu.y)};
  return q;
}

// Bulk: NSIM strips (stride 4 strips) x 16 t.
template <int NSIM>
DEVI void passN16(const ushort_t (&s_q16)[H / 4][64], const float* __restrict__ v,
                  const float* __restrict__ e4b, ushort_t (&s_sc16)[TT][S],
                  int wv, int lane) {
  float acc[NSIM][TT];
#pragma unroll
  for (int r = 0; r < NSIM; ++r)
#pragma unroll
    for (int t = 0; t < TT; ++t) acc[r][t] = 0.f;
  const float* ep = e4b + (size_t)(wv * 64 + lane) * 4;
  for (int h4 = 0; h4 < H / 4; ++h4) {
    vf4 e[NSIM];
#pragma unroll
    for (int r = 0; r < NSIM; ++r)
      e[r] = *(const vf4*)(ep + (size_t)h4 * (S * 4) + r * 1024);
    vf4 vv = *(const vf4*)(v + h4 * 4);  // wave-uniform -> s_load, K$-hot
#pragma unroll
    for (int t = 0; t < TT; ++t) {
      vf4 q = qload(s_q16, h4, t);
#pragma unroll
      for (int r = 0; r < NSIM; ++r) tree4(acc[r][t], q, vv, e[r]);
    }
  }
#pragma unroll
  for (int r = 0; r < NSIM; ++r) {
    const int s = (wv + 4 * r) * 64 + lane;
#pragma unroll
    for (int t = 0; t < TT; ++t) s_sc16[t][s] = to_bf16u(-2.0f * acc[r][t]);
  }
}

// Tail: R consecutive strips, wave computes rows {wv, wv+4, wv+8, wv+12}.
template <int R>
DEVI void passTail16(const ushort_t (&s_q16)[H / 4][64], const float* __restrict__ v,
                     const float* __restrict__ e4b, ushort_t (&s_sc16)[TT][S],
                     int kbase, int wv, int lane) {
  float acc[R][4];
#pragma unroll
  for (int r = 0; r < R; ++r)
#pragma unroll
    for (int jj = 0; jj < 4; ++jj) acc[r][jj] = 0.f;
  const float* ep = e4b + (size_t)(kbase * 64 + lane) * 4;
  for (int h4 = 0; h4 < H / 4; ++h4) {
    vf4 vv = *(const vf4*)(v + h4 * 4);
    vf4 e[R];
#pragma unroll
    for (int r = 0; r < R; ++r)
      e[r] = *(const vf4*)(ep + (size_t)h4 * (S * 4) + r * 256);
#pragma unroll
    for (int jj = 0; jj < 4; ++jj) {
      vf4 q = qload(s_q16, h4, wv + 4 * jj);
#pragma unroll
      for (int r = 0; r < R; ++r) tree4(acc[r][jj], q, vv, e[r]);
    }
  }
#pragma unroll
  for (int r = 0; r < R; ++r)
#pragma unroll
    for (int jj = 0; jj < 4; ++jj)
      s_sc16[wv + 4 * jj][(kbase + r) * 64 + lane] = to_bf16u(-2.0f * acc[r][jj]);
}

// Fused: scores -> masked softmax -> context. One block = (b, 16 timesteps).
__global__ __launch_bounds__(256, 3)
void attn_fused_kernel(const float* __restrict__ wsq, const float* __restrict__ wheT,
                       const float* __restrict__ enc, const float* __restrict__ v,
                       const int* __restrict__ lens, float* __restrict__ out) {
  __shared__ __align__(16) ushort_t s_sc16[TT][S];     // 32 KB bf16 scores/p
  __shared__ __align__(16) ushort_t s_q16[H / 4][64];  // 16 KB bf16 Q (broadcast)
  __shared__ float s_rs[TT];
  __shared__ long long s_w[32];
  __shared__ int s_bsel;

  const int tid = threadIdx.x;
  const int xcd = blockIdx.x & 7;     // dispatch round-robin heuristic
  const int j = blockIdx.x >> 3;      // 0..127
  const int slot = j >> 5;            // 0..3: which of this XCD's 4 batches
  const int tt = j & 31;              // 0..31 t-tile within batch

  // Runtime snake load-balance: rank batches by len (desc), XCD x gets ranks
  // {x, 15-x, 16+x, 31-x} -> balanced work, batch-major locality.
  if (tid < 32) s_w[tid] = ((long long)lens[tid] << 8) + tid;  // unique key
  __syncthreads();
  if (tid < 32) {
    long long wb = s_w[tid];
    int rank = 0;
#pragma unroll
    for (int b2 = 0; b2 < 32; ++b2) rank += (s_w[b2] > wb);
    int myrank = slot * 8 + ((slot & 1) ? (7 - xcd) : xcd);
    if (rank == myrank) s_bsel = tid;
  }
  __syncthreads();
  const int b = __builtin_amdgcn_readfirstlane(s_bsel);
  const int len = lens[b];

  {  // stage Q for 16 t (4 consecutive Q4 tiles = 8192 floats) as bf16
    const vf4* src = (const vf4*)(wsq + (size_t)b * T * H + (size_t)tt * (TT * H));
    uint2* dst = (uint2*)&s_q16[0][0];
#pragma unroll
    for (int u = 0; u < 8; ++u) {
      int g = tid + u * 256;            // vf4 index 0..2047
      vf4 qv = src[g];
      int tile = g >> 9, rem = g & 511;
      int h4 = rem >> 2, i = rem & 3;
      uint2 pk = make_uint2(pack_bf16(qv[0], qv[1]), pack_bf16(qv[2], qv[3]));
      dst[h4 * 16 + tile * 4 + i] = pk;
    }
  }
  __syncthreads();

  // ---- Phase A: balanced strip schedule (bulk 16t + tail 4t/wave) ----
  {
    const int wv = tid >> 6, lane = tid & 63;
    const int NS = (len + 63) >> 6;  // 1..16 strips
    const int nsw = NS >> 2;         // bulk strips per wave (0..4)
    const int R = NS & 3;            // tail strips (0..3)
    const float* e4b = wheT + (size_t)b * H * S;  // [h4][s][4]
    switch (nsw) {
      case 1: passN16<1>(s_q16, v, e4b, s_sc16, wv, lane); break;
      case 2: passN16<2>(s_q16, v, e4b, s_sc16, wv, lane); break;
      case 3: passN16<3>(s_q16, v, e4b, s_sc16, wv, lane); break;
      case 4: passN16<4>(s_q16, v, e4b, s_sc16, wv, lane); break;
      default: break;
    }
    switch (R) {
      case 1: passTail16<1>(s_q16, v, e4b, s_sc16, nsw * 4, wv, lane); break;
      case 2: passTail16<2>(s_q16, v, e4b, s_sc16, nsw * 4, wv, lane); break;
      case 3: passTail16<3>(s_q16, v, e4b, s_sc16, nsw * 4, wv, lane); break;
      default: break;
    }
  }
  __syncthreads();

  // ---- Phase B: masked softmax; wave w handles rows {w, w+4, w+8, w+12} ----
  {
    const int wv = tid >> 6, lane = tid & 63;
#pragma unroll
    for (int jj = 0; jj < 4; ++jj) {
      const int tr = wv + 4 * jj;
      float vals[S / 64], ps[S / 64];
      float m = -3.0e38f;
#pragma unroll
      for (int i = 0; i < S / 64; ++i) {
        int s = lane + 64 * i;
        vals[i] = bf_one(s_sc16[tr][s]);
        if (s < len) m = fmaxf(m, vals[i]);
      }
#pragma unroll
      for (int o = 1; o < 64; o <<= 1) m = fmaxf(m, __shfl_xor(m, o, 64));
      float sum = 0.f;
#pragma unroll
      for (int i = 0; i < S / 64; ++i) {
        int s = lane + 64 * i;
        float p = (s < len) ? __builtin_amdgcn_exp2f((vals[i] - m) * 1.44269504088896341f) : 0.f;
        ps[i] = p;
        sum += p;
      }
#pragma unroll
      for (int o = 1; o < 64; o <<= 1) sum += __shfl_xor(sum, o, 64);
      float rs = 1.0f / sum;
#pragma unroll
      for (int i = 0; i < S / 64; ++i) s_sc16[tr][lane + 64 * i] = to_bf16u(ps[i]);
      if (lane == 0) s_rs[tr] = rs;
      if (tt == T / TT - 1 && tr == TT - 1) {  // last timestep: attention weights
#pragma unroll
        for (int i = 0; i < S / 64; ++i)
          out[(size_t)B * T * H + (size_t)b * S + lane + 64 * i] = ps[i] * rs;
      }
    }
  }
  __syncthreads();

  // ---- Phase C: ctx; wave w does rows {w,w+4,w+8,w+12}, enc loads shared ----
  {
    const int wv = tid >> 6, lane = tid & 63;
    const int h0 = lane * 4, h1 = 256 + lane * 4;
    float acc[4][8] = {};
    const float* encb = enc + (size_t)b * S * H;
    const int len4 = (len + 3) & ~3;  // p == 0 beyond len, safe to over-read
    for (int s0 = 0; s0 < len4; s0 += 4) {
      vf4 pr[4];
#pragma unroll
      for (int jj = 0; jj < 4; ++jj) {
        uint2 pu = *(const uint2*)&s_sc16[wv + 4 * jj][s0];
        pr[jj] = (vf4){bf_lo(pu.x), bf_hi(pu.x), bf_lo(pu.y), bf_hi(pu.y)};
      }
#pragma unroll
      for (int kk = 0; kk < 4; ++kk) {
        const float* er = encb + (size_t)(s0 + kk) * H;
        float4 e0 = *(const float4*)(er + h0);
        float4 e1 = *(const float4*)(er + h1);
        float ev[8] = {e0.x, e0.y, e0.z, e0.w, e1.x, e1.y, e1.z, e1.w};
#pragma unroll
        for (int jj = 0; jj < 4; ++jj)
#pragma unroll
          for (int q = 0; q < 8; ++q)
            acc[jj][q] = __builtin_fmaf(pr[jj][kk], ev[q], acc[jj][q]);
      }
    }
#pragma unroll
    for (int jj = 0; jj < 4; ++jj) {
      const int tr = wv + 4 * jj;
      const float rs = s_rs[tr];
      const size_t base = ((size_t)b * T + tt * TT + tr) * H;
      float4 o;
      o = make_float4(acc[jj][0] * rs, acc[jj][1] * rs, acc[jj][2] * rs, acc[jj][3] * rs);
      *(float4*)&out[base + h0] = o;
      o = make_float4(acc[jj][4] * rs, acc[jj][5] * rs, acc[jj][6] * rs, acc[jj][7] * rs);
      *(float4*)&out[base + h1] = o;
    }
  }
}

extern "C" void kernel_launch(void* const* d_in, const int* in_sizes, int n_in,
                              void* d_out, int out_size, void* d_ws, size_t ws_size,
                              hipStream_t stream) {
  const float* query = (const float*)d_in[0];  // [B,T,H]
  const float* enc   = (const float*)d_in[1];  // [B,S,H]
  const int*   lens  = (const int*)d_in[2];    // [B]
  const float* Ws    = (const float*)d_in[3];  // [H,H]
  const float* Wh    = (const float*)d_in[4];  // [H,H]
  const float* v     = (const float*)d_in[5];  // [H]
  float* out = (float*)d_out;
  float* wsq  = (float*)d_ws;                  // Q4 [B,T/4,H/4,4,4]
  float* wheT = wsq + (size_t)B * T * H;       // E4 [B,H/4,S,4]

  mfma_matmul_kernel<<<dim3(QBLK + EBLK), 256, 0, stream>>>(query, enc, Ws, Wh, wsq, wheT, lens);
  attn_fused_kernel<<<dim3(B * (T / TT)), 256, 0, stream>>>(wsq, wheT, enc, v, lens, out);
}

// Round 17
// 560.522 us; speedup vs baseline: 1.7810x; 1.0057x over previous
//
#include <hip/hip_runtime.h>

// Bahdanau attention: B=32, T=512, S=1024, H=512, fp32.
// out = context [B,T,H] ++ attn_last [B,S]
// ws  = Q4 [B,T/4,H/4,4t,4h] ++ E4 [B,H/4,S,4] (f32); Q = e^{2*Wsq},
// E = e^{2*Whe}. Matmuls: bf16 MFMA 16x16x32, 128x128 tile (r16).
// Attn: TT=16, bf16 s_sc, balanced bulk+tail strip schedule, score' =
// sum_h (-2 v_h)/(1+Q*E) via single-rcp reciprocal tree.
// r17: 4 blocks/CU (grid 1024 fully resident, kills the 2-round dispatch
// tail seen as Occupancy=29%): s_q shrunk to a 4KB quarter-buffer restaged
// 4x inside Phase A (acc persists in regs; barriers block-uniform).

constexpr int B = 32, T = 512, S = 1024, H = 512;
constexpr int TT = 16;  // timesteps per attn block
constexpr float C2LOG2E = 2.88539008177792681f;  // 2*log2(e)

typedef float vf4 __attribute__((ext_vector_type(4)));
typedef float f32x4 __attribute__((ext_vector_type(4)));
typedef short bf16x8 __attribute__((ext_vector_type(8)));
typedef unsigned short ushort_t;

#define DEVI __device__ __forceinline__

DEVI unsigned pack_bf16(float a, float b) {  // round-half-up; safe (no inf inputs)
  unsigned ua = __builtin_bit_cast(unsigned, a) + 0x8000u;
  unsigned ub = __builtin_bit_cast(unsigned, b) + 0x8000u;
  return (ub & 0xffff0000u) | (ua >> 16);
}
DEVI ushort_t to_bf16u(float x) {
  return (ushort_t)((__builtin_bit_cast(unsigned, x) + 0x8000u) >> 16);
}
DEVI float bf_lo(unsigned d) { return __builtin_bit_cast(float, d << 16); }
DEVI float bf_hi(unsigned d) { return __builtin_bit_cast(float, d & 0xffff0000u); }
DEVI float bf_one(ushort_t u) { return __builtin_bit_cast(float, (unsigned)u << 16); }
DEVI float exp2c(float x) {
  return __builtin_amdgcn_exp2f(fminf(fmaxf(x, -15.f), 15.f));
}

// ---- MFMA matmul: Cout = exp2(clamp(scale * A[M,512] * W[512,512]^T)) ----
constexpr int QBLK = (B * T / 128) * 4;  // 512
constexpr int EBLK = (B * S / 128) * 4;  // 1024

__global__ __launch_bounds__(256)
void mfma_matmul_kernel(const float* __restrict__ query, const float* __restrict__ enc,
                        const float* __restrict__ Ws, const float* __restrict__ Wh,
                        float* __restrict__ q4, float* __restrict__ e4,
                        const int* __restrict__ lens) {
  __shared__ short As[128][72];  // bf16 A-tile chunk [m][k], +8 pad
  __shared__ short Bs[128][72];  // bf16 W-tile chunk [n][k], +8 pad
  const int tid = threadIdx.x;
  int blk = blockIdx.x;
  const bool isE = blk >= QBLK;
  if (isE) blk -= QBLK;
  const int bx = blk & 3, by = blk >> 2;
  const int row0 = by * 128, col0 = bx * 128;
  const float* A = isE ? enc : query;
  const float* W = isE ? Wh : Ws;
  if (isE && (row0 % S) >= lens[row0 / S]) return;  // fully-masked s-tile

  const int lr = tid >> 4;        // 0..15 (row group for staging)
  const int lc = (tid & 15) * 4;  // 0..60 (k cols for staging)
  const int lane = tid & 63, wv = tid >> 6;
  const int wm = (wv >> 1) * 64, wn = (wv & 1) * 64;
  const int lrow = lane & 15, lkg = (lane >> 4) * 8;

  f32x4 acc[4][4] = {};
  for (int k0 = 0; k0 < H; k0 += 64) {
    __syncthreads();
#pragma unroll
    for (int u = 0; u < 8; ++u) {
      int r = lr + u * 16;
      float4 av = *(const float4*)&A[(size_t)(row0 + r) * H + k0 + lc];
      *(uint2*)&As[r][lc] = make_uint2(pack_bf16(av.x, av.y), pack_bf16(av.z, av.w));
      float4 wv4 = *(const float4*)&W[(size_t)(col0 + r) * H + k0 + lc];
      *(uint2*)&Bs[r][lc] = make_uint2(pack_bf16(wv4.x, wv4.y), pack_bf16(wv4.z, wv4.w));
    }
    __syncthreads();
#pragma unroll
    for (int ks = 0; ks < 64; ks += 32) {
      bf16x8 af[4], bfr[4];
#pragma unroll
      for (int i = 0; i < 4; ++i) {
        af[i] = *(const bf16x8*)&As[wm + i * 16 + lrow][ks + lkg];
        bfr[i] = *(const bf16x8*)&Bs[wn + i * 16 + lrow][ks + lkg];
      }
#pragma unroll
      for (int mt = 0; mt < 4; ++mt)
#pragma unroll
        for (int nt = 0; nt < 4; ++nt)
          acc[mt][nt] = __builtin_amdgcn_mfma_f32_16x16x32_bf16(
              af[mt], bfr[nt], acc[mt][nt], 0, 0, 0);
    }
  }

  // Epilogue: C frag layout col=lane&15, row=(lane>>4)*4+reg (m89-verified).
  const int crow = (lane >> 4) * 4, ccol = lane & 15;
  if (!isE) {
    const int b = row0 / T;
#pragma unroll
    for (int mt = 0; mt < 4; ++mt) {
      const int m = (row0 % T) + wm + mt * 16 + crow;  // multiple of 4
      const int tile_t = m >> 2;
#pragma unroll
      for (int nt = 0; nt < 4; ++nt) {
        const int n = col0 + wn + nt * 16 + ccol;
        float* base = q4 + (size_t)b * T * H + (size_t)tile_t * (4 * H) +
                      (n >> 2) * 16 + (n & 3);
        f32x4 a = acc[mt][nt];
#pragma unroll
        for (int reg = 0; reg < 4; ++reg) base[reg * 4] = exp2c(C2LOG2E * a[reg]);
      }
    }
  } else {
    const int b = row0 / S;
#pragma unroll
    for (int mt = 0; mt < 4; ++mt) {
      const int s0 = (row0 % S) + wm + mt * 16 + crow;
#pragma unroll
      for (int nt = 0; nt < 4; ++nt) {
        const int n = col0 + wn + nt * 16 + ccol;
        float* base = e4 + (size_t)b * H * S + (size_t)(n >> 2) * (4 * S) +
                      (size_t)s0 * 4 + (n & 3);
        f32x4 a = acc[mt][nt];
#pragma unroll
        for (int reg = 0; reg < 4; ++reg) base[reg * 4] = exp2c(C2LOG2E * a[reg]);
      }
    }
  }
}

// acc += sum_{i<4} vv[i] / (1 + q[i]*e[i]) via single-rcp reciprocal tree.
DEVI void tree4(float& acc, vf4 q, vf4 vv, vf4 e) {
  float a0 = __builtin_fmaf(q[0], e[0], 1.0f);
  float a1 = __builtin_fmaf(q[1], e[1], 1.0f);
  float a2 = __builtin_fmaf(q[2], e[2], 1.0f);
  float a3 = __builtin_fmaf(q[3], e[3], 1.0f);
  float d01 = a0 * a1, d23 = a2 * a3;
  float n01 = __builtin_fmaf(vv[1], a0, vv[0] * a1);
  float n23 = __builtin_fmaf(vv[3], a2, vv[2] * a3);
  float d = d01 * d23;
  float n = __builtin_fmaf(n23, d01, n01 * d23);
  acc = __builtin_fmaf(n, __builtin_amdgcn_rcpf(d), acc);
}

DEVI vf4 qload4(const ushort_t (&s_q4)[32][64], int h4q, int t) {
  uint2 qu = *(const uint2*)&s_q4[h4q][t * 4];
  vf4 q = {bf_lo(qu.x), bf_hi(qu.x), bf_lo(qu.y), bf_hi(qu.y)};
  return q;
}

// Stage one h-quarter (32 h4 rows x 16 t) of Q into the 4KB buffer.
DEVI void stage_quarter(ushort_t (&s_q4)[32][64], const vf4* __restrict__ qsrc,
                        int qt, int tid) {
  __syncthreads();  // previous-quarter reads done (uniform across waves)
#pragma unroll
  for (int u = 0; u < 2; ++u) {
    int g = tid + u * 256;                 // 0..511
    int tile = g >> 7, rem = g & 127;
    int h4q = rem >> 2, i = rem & 3;
    vf4 qv = qsrc[tile * 512 + (qt * 32 + h4q) * 4 + i];
    uint2 pk = make_uint2(pack_bf16(qv[0], qv[1]), pack_bf16(qv[2], qv[3]));
    ((uint2*)&s_q4[0][0])[h4q * 16 + tile * 4 + i] = pk;
  }
  __syncthreads();
}

// Bulk: NSIM strips (stride 4 strips) x 16 t; q restaged per h-quarter.
template <int NSIM>
DEVI void passN16(ushort_t (&s_q4)[32][64], const vf4* __restrict__ qsrc,
                  const float* __restrict__ v, const float* __restrict__ e4b,
                  ushort_t (&s_sc16)[TT][S], int wv, int lane) {
  const int tid = wv * 64 + lane;
  float acc[NSIM][TT];
#pragma unroll
  for (int r = 0; r < NSIM; ++r)
#pragma unroll
    for (int t = 0; t < TT; ++t) acc[r][t] = 0.f;
  const float* ep = e4b + (size_t)(wv * 64 + lane) * 4;
  for (int qt = 0; qt < 4; ++qt) {
    stage_quarter(s_q4, qsrc, qt, tid);
    for (int h4q = 0; h4q < 32; ++h4q) {
      const int h4 = qt * 32 + h4q;
      vf4 e[NSIM];
#pragma unroll
      for (int r = 0; r < NSIM; ++r)
        e[r] = *(const vf4*)(ep + (size_t)h4 * (S * 4) + r * 1024);
      vf4 vv = *(const vf4*)(v + h4 * 4);  // wave-uniform -> s_load, K$-hot
#pragma unroll
      for (int t = 0; t < TT; ++t) {
        vf4 q = qload4(s_q4, h4q, t);
#pragma unroll
        for (int r = 0; r < NSIM; ++r) tree4(acc[r][t], q, vv, e[r]);
      }
    }
  }
#pragma unroll
  for (int r = 0; r < NSIM; ++r) {
    const int s = (wv + 4 * r) * 64 + lane;
#pragma unroll
    for (int t = 0; t < TT; ++t) s_sc16[t][s] = to_bf16u(-2.0f * acc[r][t]);
  }
}

// Tail: R consecutive strips, wave computes rows {wv, wv+4, wv+8, wv+12}.
template <int R>
DEVI void passTail16(ushort_t (&s_q4)[32][64], const vf4* __restrict__ qsrc,
                     const float* __restrict__ v, const float* __restrict__ e4b,
                     ushort_t (&s_sc16)[TT][S], int kbase, int wv, int lane) {
  const int tid = wv * 64 + lane;
  float acc[R][4];
#pragma unroll
  for (int r = 0; r < R; ++r)
#pragma unroll
    for (int jj = 0; jj < 4; ++jj) acc[r][jj] = 0.f;
  const float* ep = e4b + (size_t)(kbase * 64 + lane) * 4;
  for (int qt = 0; qt < 4; ++qt) {
    stage_quarter(s_q4, qsrc, qt, tid);
    for (int h4q = 0; h4q < 32; ++h4q) {
      const int h4 = qt * 32 + h4q;
      vf4 vv = *(const vf4*)(v + h4 * 4);
      vf4 e[R];
#pragma unroll
      for (int r = 0; r < R; ++r)
        e[r] = *(const vf4*)(ep + (size_t)h4 * (S * 4) + r * 256);
#pragma unroll
      for (int jj = 0; jj < 4; ++jj) {
        vf4 q = qload4(s_q4, h4q, wv + 4 * jj);
#pragma unroll
        for (int r = 0; r < R; ++r) tree4(acc[r][jj], q, vv, e[r]);
      }
    }
  }
#pragma unroll
  for (int r = 0; r < R; ++r)
#pragma unroll
    for (int jj = 0; jj < 4; ++jj)
      s_sc16[wv + 4 * jj][(kbase + r) * 64 + lane] = to_bf16u(-2.0f * acc[r][jj]);
}

// Fused: scores -> masked softmax -> context. One block = (b, 16 timesteps).
__global__ __launch_bounds__(256, 4)
void attn_fused_kernel(const float* __restrict__ wsq, const float* __restrict__ wheT,
                       const float* __restrict__ enc, const float* __restrict__ v,
                       const int* __restrict__ lens, float* __restrict__ out) {
  __shared__ __align__(16) ushort_t s_sc16[TT][S];   // 32 KB bf16 scores/p
  __shared__ __align__(16) ushort_t s_q4[32][64];    // 4 KB bf16 Q quarter
  __shared__ float s_rs[TT];
  __shared__ long long s_w[32];
  __shared__ int s_bsel;

  const int tid = threadIdx.x;
  const int xcd = blockIdx.x & 7;     // dispatch round-robin heuristic
  const int j = blockIdx.x >> 3;      // 0..127
  const int slot = j >> 5;            // 0..3: which of this XCD's 4 batches
  const int tt = j & 31;              // 0..31 t-tile within batch

  // Runtime snake load-balance: rank batches by len (desc), XCD x gets ranks
  // {x, 15-x, 16+x, 31-x} -> balanced work, batch-major locality.
  if (tid < 32) s_w[tid] = ((long long)lens[tid] << 8) + tid;  // unique key
  __syncthreads();
  if (tid < 32) {
    long long wb = s_w[tid];
    int rank = 0;
#pragma unroll
    for (int b2 = 0; b2 < 32; ++b2) rank += (s_w[b2] > wb);
    int myrank = slot * 8 + ((slot & 1) ? (7 - xcd) : xcd);
    if (rank == myrank) s_bsel = tid;
  }
  __syncthreads();
  const int b = __builtin_amdgcn_readfirstlane(s_bsel);
  const int len = lens[b];

  // ---- Phase A: balanced strip schedule (bulk 16t + tail 4t/wave);
  // q staged per h-quarter into the 4KB buffer inside the passes. ----
  {
    const int wv = tid >> 6, lane = tid & 63;
    const int NS = (len + 63) >> 6;  // 1..16 strips
    const int nsw = NS >> 2;         // bulk strips per wave (0..4)
    const int R = NS & 3;            // tail strips (0..3)
    const float* e4b = wheT + (size_t)b * H * S;  // [h4][s][4]
    const vf4* qsrc = (const vf4*)(wsq + (size_t)b * T * H + (size_t)tt * (TT * H));
    switch (nsw) {
      case 1: passN16<1>(s_q4, qsrc, v, e4b, s_sc16, wv, lane); break;
      case 2: passN16<2>(s_q4, qsrc, v, e4b, s_sc16, wv, lane); break;
      case 3: passN16<3>(s_q4, qsrc, v, e4b, s_sc16, wv, lane); break;
      case 4: passN16<4>(s_q4, qsrc, v, e4b, s_sc16, wv, lane); break;
      default: break;
    }
    switch (R) {
      case 1: passTail16<1>(s_q4, qsrc, v, e4b, s_sc16, nsw * 4, wv, lane); break;
      case 2: passTail16<2>(s_q4, qsrc, v, e4b, s_sc16, nsw * 4, wv, lane); break;
      case 3: passTail16<3>(s_q4, qsrc, v, e4b, s_sc16, nsw * 4, wv, lane); break;
      default: break;
    }
  }
  __syncthreads();

  // ---- Phase B: masked softmax; wave w handles rows {w, w+4, w+8, w+12} ----
  {
    const int wv = tid >> 6, lane = tid & 63;
#pragma unroll
    for (int jj = 0; jj < 4; ++jj) {
      const int tr = wv + 4 * jj;
      float vals[S / 64], ps[S / 64];
      float m = -3.0e38f;
#pragma unroll
      for (int i = 0; i < S / 64; ++i) {
        int s = lane + 64 * i;
        vals[i] = bf_one(s_sc16[tr][s]);
        if (s < len) m = fmaxf(m, vals[i]);
      }
#pragma unroll
      for (int o = 1; o < 64; o <<= 1) m = fmaxf(m, __shfl_xor(m, o, 64));
      float sum = 0.f;
#pragma unroll
      for (int i = 0; i < S / 64; ++i) {
        int s = lane + 64 * i;
        float p = (s < len) ? __builtin_amdgcn_exp2f((vals[i] - m) * 1.44269504088896341f) : 0.f;
        ps[i] = p;
        sum += p;
      }
#pragma unroll
      for (int o = 1; o < 64; o <<= 1) sum += __shfl_xor(sum, o, 64);
      float rs = 1.0f / sum;
#pragma unroll
      for (int i = 0; i < S / 64; ++i) s_sc16[tr][lane + 64 * i] = to_bf16u(ps[i]);
      if (lane == 0) s_rs[tr] = rs;
      if (tt == T / TT - 1 && tr == TT - 1) {  // last timestep: attention weights
#pragma unroll
        for (int i = 0; i < S / 64; ++i)
          out[(size_t)B * T * H + (size_t)b * S + lane + 64 * i] = ps[i] * rs;
      }
    }
  }
  __syncthreads();

  // ---- Phase C: ctx; wave w does rows {w,w+4,w+8,w+12}, enc loads shared ----
  {
    const int wv = tid >> 6, lane = tid & 63;
    const int h0 = lane * 4, h1 = 256 + lane * 4;
    float acc[4][8] = {};
    const float* encb = enc + (size_t)b * S * H;
    const int len4 = (len + 3) & ~3;  // p == 0 beyond len, safe to over-read
    for (int s0 = 0; s0 < len4; s0 += 4) {
      vf4 pr[4];
#pragma unroll
      for (int jj = 0; jj < 4; ++jj) {
        uint2 pu = *(const uint2*)&s_sc16[wv + 4 * jj][s0];
        pr[jj] = (vf4){bf_lo(pu.x), bf_hi(pu.x), bf_lo(pu.y), bf_hi(pu.y)};
      }
#pragma unroll
      for (int kk = 0; kk < 4; ++kk) {
        const float* er = encb + (size_t)(s0 + kk) * H;
        float4 e0 = *(const float4*)(er + h0);
        float4 e1 = *(const float4*)(er + h1);
        float ev[8] = {e0.x, e0.y, e0.z, e0.w, e1.x, e1.y, e1.z, e1.w};
#pragma unroll
        for (int jj = 0; jj < 4; ++jj)
#pragma unroll
          for (int q = 0; q < 8; ++q)
            acc[jj][q] = __builtin_fmaf(pr[jj][kk], ev[q], acc[jj][q]);
      }
    }
#pragma unroll
    for (int jj = 0; jj < 4; ++jj) {
      const int tr = wv + 4 * jj;
      const float rs = s_rs[tr];
      const size_t base = ((size_t)b * T + tt * TT + tr) * H;
      float4 o;
      o = make_float4(acc[jj][0] * rs, acc[jj][1] * rs, acc[jj][2] * rs, acc[jj][3] * rs);
      *(float4*)&out[base + h0] = o;
      o = make_float4(acc[jj][4] * rs, acc[jj][5] * rs, acc[jj][6] * rs, acc[jj][7] * rs);
      *(float4*)&out[base + h1] = o;
    }
  }
}

extern "C" void kernel_launch(void* const* d_in, const int* in_sizes, int n_in,
                              void* d_out, int out_size, void* d_ws, size_t ws_size,
                              hipStream_t stream) {
  const float* query = (const float*)d_in[0];  // [B,T,H]
  const float* enc   = (const float*)d_in[1];  // [B,S,H]
  const int*   lens  = (const int*)d_in[2];    // [B]
  const float* Ws    = (const float*)d_in[3];  // [H,H]
  const float* Wh    = (const float*)d_in[4];  // [H,H]
  const float* v     = (const float*)d_in[5];  // [H]
  float* out = (float*)d_out;
  float* wsq  = (float*)d_ws;                  // Q4 [B,T/4,H/4,4,4]
  float* wheT = wsq + (size_t)B * T * H;       // E4 [B,H/4,S,4]

  mfma_matmul_kernel<<<dim3(QBLK + EBLK), 256, 0, stream>>>(query, enc, Ws, Wh, wsq, wheT, lens);
  attn_fused_kernel<<<dim3(B * (T / TT)), 256, 0, stream>>>(wsq, wheT, enc, v, lens, out);
}

// Round 18
// 489.110 us; speedup vs baseline: 2.0410x; 1.1460x over previous
//
#include <hip/hip_runtime.h>

// Bahdanau attention: B=32, T=512, S=1024, H=512, fp32.
// out = context [B,T,H] ++ attn_last [B,S]
// ws  = Q4 [B,T/4,H/4,4t,4h] ++ E4 [B,H/4,S,4] (f32); Q = e^{2*Wsq},
// E = e^{2*Whe}. Matmuls: bf16 MFMA 16x16x32, 128x128 tile (r16).
// Attn: TT=16, bf16 s_sc (+8 pad), balanced bulk+tail strip schedule,
// score' = sum_h (-2 v_h)/(1+Q*E) via single-rcp reciprocal tree; 4 blk/CU.
// r18: Phase C on MFMA (P from LDS as A-frags, enc cols packed bf16 as
// B-frags, D written direct); softmax max-pass dropped (|score|<=36 << 88,
// shift-invariant); P stored normalized in Phase B.

constexpr int B = 32, T = 512, S = 1024, H = 512;
constexpr int TT = 16;   // timesteps per attn block
constexpr int SP = S + 8;  // padded s_sc row (2-way instead of 16-way bank alias)
constexpr float C2LOG2E = 2.88539008177792681f;  // 2*log2(e)

typedef float vf4 __attribute__((ext_vector_type(4)));
typedef float f32x4 __attribute__((ext_vector_type(4)));
typedef short bf16x8 __attribute__((ext_vector_type(8)));
typedef unsigned short ushort_t;

#define DEVI __device__ __forceinline__

DEVI unsigned pack_bf16(float a, float b) {  // round-half-up; safe (no inf inputs)
  unsigned ua = __builtin_bit_cast(unsigned, a) + 0x8000u;
  unsigned ub = __builtin_bit_cast(unsigned, b) + 0x8000u;
  return (ub & 0xffff0000u) | (ua >> 16);
}
DEVI ushort_t to_bf16u(float x) {
  return (ushort_t)((__builtin_bit_cast(unsigned, x) + 0x8000u) >> 16);
}
DEVI float bf_lo(unsigned d) { return __builtin_bit_cast(float, d << 16); }
DEVI float bf_hi(unsigned d) { return __builtin_bit_cast(float, d & 0xffff0000u); }
DEVI float bf_one(ushort_t u) { return __builtin_bit_cast(float, (unsigned)u << 16); }
DEVI float exp2c(float x) {
  return __builtin_amdgcn_exp2f(fminf(fmaxf(x, -15.f), 15.f));
}

// ---- MFMA matmul: Cout = exp2(clamp(scale * A[M,512] * W[512,512]^T)) ----
constexpr int QBLK = (B * T / 128) * 4;  // 512
constexpr int EBLK = (B * S / 128) * 4;  // 1024

__global__ __launch_bounds__(256)
void mfma_matmul_kernel(const float* __restrict__ query, const float* __restrict__ enc,
                        const float* __restrict__ Ws, const float* __restrict__ Wh,
                        float* __restrict__ q4, float* __restrict__ e4,
                        const int* __restrict__ lens) {
  __shared__ short As[128][72];  // bf16 A-tile chunk [m][k], +8 pad
  __shared__ short Bs[128][72];  // bf16 W-tile chunk [n][k], +8 pad
  const int tid = threadIdx.x;
  int blk = blockIdx.x;
  const bool isE = blk >= QBLK;
  if (isE) blk -= QBLK;
  const int bx = blk & 3, by = blk >> 2;
  const int row0 = by * 128, col0 = bx * 128;
  const float* A = isE ? enc : query;
  const float* W = isE ? Wh : Ws;
  if (isE && (row0 % S) >= lens[row0 / S]) return;  // fully-masked s-tile

  const int lr = tid >> 4;        // 0..15 (row group for staging)
  const int lc = (tid & 15) * 4;  // 0..60 (k cols for staging)
  const int lane = tid & 63, wv = tid >> 6;
  const int wm = (wv >> 1) * 64, wn = (wv & 1) * 64;
  const int lrow = lane & 15, lkg = (lane >> 4) * 8;

  f32x4 acc[4][4] = {};
  for (int k0 = 0; k0 < H; k0 += 64) {
    __syncthreads();
#pragma unroll
    for (int u = 0; u < 8; ++u) {
      int r = lr + u * 16;
      float4 av = *(const float4*)&A[(size_t)(row0 + r) * H + k0 + lc];
      *(uint2*)&As[r][lc] = make_uint2(pack_bf16(av.x, av.y), pack_bf16(av.z, av.w));
      float4 wv4 = *(const float4*)&W[(size_t)(col0 + r) * H + k0 + lc];
      *(uint2*)&Bs[r][lc] = make_uint2(pack_bf16(wv4.x, wv4.y), pack_bf16(wv4.z, wv4.w));
    }
    __syncthreads();
#pragma unroll
    for (int ks = 0; ks < 64; ks += 32) {
      bf16x8 af[4], bfr[4];
#pragma unroll
      for (int i = 0; i < 4; ++i) {
        af[i] = *(const bf16x8*)&As[wm + i * 16 + lrow][ks + lkg];
        bfr[i] = *(const bf16x8*)&Bs[wn + i * 16 + lrow][ks + lkg];
      }
#pragma unroll
      for (int mt = 0; mt < 4; ++mt)
#pragma unroll
        for (int nt = 0; nt < 4; ++nt)
          acc[mt][nt] = __builtin_amdgcn_mfma_f32_16x16x32_bf16(
              af[mt], bfr[nt], acc[mt][nt], 0, 0, 0);
    }
  }

  // Epilogue: C frag layout col=lane&15, row=(lane>>4)*4+reg (m89-verified).
  const int crow = (lane >> 4) * 4, ccol = lane & 15;
  if (!isE) {
    const int b = row0 / T;
#pragma unroll
    for (int mt = 0; mt < 4; ++mt) {
      const int m = (row0 % T) + wm + mt * 16 + crow;  // multiple of 4
      const int tile_t = m >> 2;
#pragma unroll
      for (int nt = 0; nt < 4; ++nt) {
        const int n = col0 + wn + nt * 16 + ccol;
        float* base = q4 + (size_t)b * T * H + (size_t)tile_t * (4 * H) +
                      (n >> 2) * 16 + (n & 3);
        f32x4 a = acc[mt][nt];
#pragma unroll
        for (int reg = 0; reg < 4; ++reg) base[reg * 4] = exp2c(C2LOG2E * a[reg]);
      }
    }
  } else {
    const int b = row0 / S;
#pragma unroll
    for (int mt = 0; mt < 4; ++mt) {
      const int s0 = (row0 % S) + wm + mt * 16 + crow;
#pragma unroll
      for (int nt = 0; nt < 4; ++nt) {
        const int n = col0 + wn + nt * 16 + ccol;
        float* base = e4 + (size_t)b * H * S + (size_t)(n >> 2) * (4 * S) +
                      (size_t)s0 * 4 + (n & 3);
        f32x4 a = acc[mt][nt];
#pragma unroll
        for (int reg = 0; reg < 4; ++reg) base[reg * 4] = exp2c(C2LOG2E * a[reg]);
      }
    }
  }
}

// acc += sum_{i<4} vv[i] / (1 + q[i]*e[i]) via single-rcp reciprocal tree.
DEVI void tree4(float& acc, vf4 q, vf4 vv, vf4 e) {
  float a0 = __builtin_fmaf(q[0], e[0], 1.0f);
  float a1 = __builtin_fmaf(q[1], e[1], 1.0f);
  float a2 = __builtin_fmaf(q[2], e[2], 1.0f);
  float a3 = __builtin_fmaf(q[3], e[3], 1.0f);
  float d01 = a0 * a1, d23 = a2 * a3;
  float n01 = __builtin_fmaf(vv[1], a0, vv[0] * a1);
  float n23 = __builtin_fmaf(vv[3], a2, vv[2] * a3);
  float d = d01 * d23;
  float n = __builtin_fmaf(n23, d01, n01 * d23);
  acc = __builtin_fmaf(n, __builtin_amdgcn_rcpf(d), acc);
}

DEVI vf4 qload4(const ushort_t (&s_q4)[32][64], int h4q, int t) {
  uint2 qu = *(const uint2*)&s_q4[h4q][t * 4];
  vf4 q = {bf_lo(qu.x), bf_hi(qu.x), bf_lo(qu.y), bf_hi(qu.y)};
  return q;
}

// Stage one h-quarter (32 h4 rows x 16 t) of Q into the 4KB buffer.
DEVI void stage_quarter(ushort_t (&s_q4)[32][64], const vf4* __restrict__ qsrc,
                        int qt, int tid) {
  __syncthreads();  // previous-quarter reads done (uniform across waves)
#pragma unroll
  for (int u = 0; u < 2; ++u) {
    int g = tid + u * 256;                 // 0..511
    int tile = g >> 7, rem = g & 127;
    int h4q = rem >> 2, i = rem & 3;
    vf4 qv = qsrc[tile * 512 + (qt * 32 + h4q) * 4 + i];
    uint2 pk = make_uint2(pack_bf16(qv[0], qv[1]), pack_bf16(qv[2], qv[3]));
    ((uint2*)&s_q4[0][0])[h4q * 16 + tile * 4 + i] = pk;
  }
  __syncthreads();
}

// Bulk: NSIM strips (stride 4 strips) x 16 t; q restaged per h-quarter.
template <int NSIM>
DEVI void passN16(ushort_t (&s_q4)[32][64], const vf4* __restrict__ qsrc,
                  const float* __restrict__ v, const float* __restrict__ e4b,
                  ushort_t (&s_sc16)[TT][SP], int wv, int lane) {
  const int tid = wv * 64 + lane;
  float acc[NSIM][TT];
#pragma unroll
  for (int r = 0; r < NSIM; ++r)
#pragma unroll
    for (int t = 0; t < TT; ++t) acc[r][t] = 0.f;
  const float* ep = e4b + (size_t)(wv * 64 + lane) * 4;
  for (int qt = 0; qt < 4; ++qt) {
    stage_quarter(s_q4, qsrc, qt, tid);
    for (int h4q = 0; h4q < 32; ++h4q) {
      const int h4 = qt * 32 + h4q;
      vf4 e[NSIM];
#pragma unroll
      for (int r = 0; r < NSIM; ++r)
        e[r] = *(const vf4*)(ep + (size_t)h4 * (S * 4) + r * 1024);
      vf4 vv = *(const vf4*)(v + h4 * 4);  // wave-uniform -> s_load, K$-hot
#pragma unroll
      for (int t = 0; t < TT; ++t) {
        vf4 q = qload4(s_q4, h4q, t);
#pragma unroll
        for (int r = 0; r < NSIM; ++r) tree4(acc[r][t], q, vv, e[r]);
      }
    }
  }
#pragma unroll
  for (int r = 0; r < NSIM; ++r) {
    const int s = (wv + 4 * r) * 64 + lane;
#pragma unroll
    for (int t = 0; t < TT; ++t) s_sc16[t][s] = to_bf16u(-2.0f * acc[r][t]);
  }
}

// Tail: R consecutive strips, wave computes rows {wv, wv+4, wv+8, wv+12}.
template <int R>
DEVI void passTail16(ushort_t (&s_q4)[32][64], const vf4* __restrict__ qsrc,
                     const float* __restrict__ v, const float* __restrict__ e4b,
                     ushort_t (&s_sc16)[TT][SP], int kbase, int wv, int lane) {
  const int tid = wv * 64 + lane;
  float acc[R][4];
#pragma unroll
  for (int r = 0; r < R; ++r)
#pragma unroll
    for (int jj = 0; jj < 4; ++jj) acc[r][jj] = 0.f;
  const float* ep = e4b + (size_t)(kbase * 64 + lane) * 4;
  for (int qt = 0; qt < 4; ++qt) {
    stage_quarter(s_q4, qsrc, qt, tid);
    for (int h4q = 0; h4q < 32; ++h4q) {
      const int h4 = qt * 32 + h4q;
      vf4 vv = *(const vf4*)(v + h4 * 4);
      vf4 e[R];
#pragma unroll
      for (int r = 0; r < R; ++r)
        e[r] = *(const vf4*)(ep + (size_t)h4 * (S * 4) + r * 256);
#pragma unroll
      for (int jj = 0; jj < 4; ++jj) {
        vf4 q = qload4(s_q4, h4q, wv + 4 * jj);
#pragma unroll
        for (int r = 0; r < R; ++r) tree4(acc[r][jj], q, vv, e[r]);
      }
    }
  }
#pragma unroll
  for (int r = 0; r < R; ++r)
#pragma unroll
    for (int jj = 0; jj < 4; ++jj)
      s_sc16[wv + 4 * jj][(kbase + r) * 64 + lane] = to_bf16u(-2.0f * acc[r][jj]);
}

// Fused: scores -> masked softmax -> context. One block = (b, 16 timesteps).
__global__ __launch_bounds__(256, 4)
void attn_fused_kernel(const float* __restrict__ wsq, const float* __restrict__ wheT,
                       const float* __restrict__ enc, const float* __restrict__ v,
                       const int* __restrict__ lens, float* __restrict__ out) {
  __shared__ __align__(16) ushort_t s_sc16[TT][SP];  // 33 KB bf16 scores -> p
  __shared__ __align__(16) ushort_t s_q4[32][64];    // 4 KB bf16 Q quarter
  __shared__ long long s_w[32];
  __shared__ int s_bsel;

  const int tid = threadIdx.x;
  const int xcd = blockIdx.x & 7;     // dispatch round-robin heuristic
  const int j = blockIdx.x >> 3;      // 0..127
  const int slot = j >> 5;            // 0..3: which of this XCD's 4 batches
  const int tt = j & 31;              // 0..31 t-tile within batch

  // Runtime snake load-balance: rank batches by len (desc), XCD x gets ranks
  // {x, 15-x, 16+x, 31-x} -> balanced work, batch-major locality.
  if (tid < 32) s_w[tid] = ((long long)lens[tid] << 8) + tid;  // unique key
  __syncthreads();
  if (tid < 32) {
    long long wb = s_w[tid];
    int rank = 0;
#pragma unroll
    for (int b2 = 0; b2 < 32; ++b2) rank += (s_w[b2] > wb);
    int myrank = slot * 8 + ((slot & 1) ? (7 - xcd) : xcd);
    if (rank == myrank) s_bsel = tid;
  }
  __syncthreads();
  const int b = __builtin_amdgcn_readfirstlane(s_bsel);
  const int len = lens[b];

  // ---- Phase A: balanced strip schedule (bulk 16t + tail 4t/wave);
  // q staged per h-quarter into the 4KB buffer inside the passes. ----
  {
    const int wv = tid >> 6, lane = tid & 63;
    const int NS = (len + 63) >> 6;  // 1..16 strips
    const int nsw = NS >> 2;         // bulk strips per wave (0..4)
    const int R = NS & 3;            // tail strips (0..3)
    const float* e4b = wheT + (size_t)b * H * S;  // [h4][s][4]
    const vf4* qsrc = (const vf4*)(wsq + (size_t)b * T * H + (size_t)tt * (TT * H));
    switch (nsw) {
      case 1: passN16<1>(s_q4, qsrc, v, e4b, s_sc16, wv, lane); break;
      case 2: passN16<2>(s_q4, qsrc, v, e4b, s_sc16, wv, lane); break;
      case 3: passN16<3>(s_q4, qsrc, v, e4b, s_sc16, wv, lane); break;
      case 4: passN16<4>(s_q4, qsrc, v, e4b, s_sc16, wv, lane); break;
      default: break;
    }
    switch (R) {
      case 1: passTail16<1>(s_q4, qsrc, v, e4b, s_sc16, nsw * 4, wv, lane); break;
      case 2: passTail16<2>(s_q4, qsrc, v, e4b, s_sc16, nsw * 4, wv, lane); break;
      case 3: passTail16<3>(s_q4, qsrc, v, e4b, s_sc16, nsw * 4, wv, lane); break;
      default: break;
    }
  }
  __syncthreads();

  // ---- Phase B: softmax WITHOUT max-shift (|score| <= 2*||v||_1 ~ 36 << 88,
  // softmax is shift-invariant); store NORMALIZED p (bf16). Wave w: rows
  // {w, w+4, w+8, w+12}. ----
  {
    const int wv = tid >> 6, lane = tid & 63;
#pragma unroll
    for (int jj = 0; jj < 4; ++jj) {
      const int tr = wv + 4 * jj;
      float ps[S / 64];
      float sum = 0.f;
#pragma unroll
      for (int i = 0; i < S / 64; ++i) {
        int s = lane + 64 * i;
        float sc = bf_one(s_sc16[tr][s]);
        float p = (s < len) ? __builtin_amdgcn_exp2f(sc * 1.44269504088896341f) : 0.f;
        ps[i] = p;
        sum += p;
      }
#pragma unroll
      for (int o = 1; o < 64; o <<= 1) sum += __shfl_xor(sum, o, 64);
      float rs = 1.0f / sum;
#pragma unroll
      for (int i = 0; i < S / 64; ++i) {
        float pn = ps[i] * rs;
        s_sc16[tr][lane + 64 * i] = to_bf16u(pn);
        if (tt == T / TT - 1 && tr == TT - 1)  // last timestep: attn weights
          out[(size_t)B * T * H + (size_t)b * S + lane + 64 * i] = pn;
      }
    }
  }
  __syncthreads();

  // ---- Phase C on MFMA: ctx[16t][512h] = P[16xS] * enc[Sx512].
  // A-frag = P rows from s_sc16 (padded -> 2-way alias only); B-frag = enc
  // columns loaded per-lane (16 consecutive h per lane-group = 64B txns),
  // packed bf16. D layout: col=lane&15 (h), row=(lane>>4)*4+reg (t). ----
  {
    const int wv = tid >> 6, lane = tid & 63;
    const int lrow = lane & 15, lkg = (lane >> 4) * 8;
    const int hbase = wv * 128;
    const float* encb = enc + (size_t)b * S * H;
    f32x4 acc[8] = {};
    const int nch = (len + 31) >> 5;  // k-chunks of 32 s (P==0 beyond len)
    for (int kc = 0; kc < nch; ++kc) {
      const int k0 = kc * 32 + lkg;
      bf16x8 pa = *(const bf16x8*)&s_sc16[lrow][k0];
#pragma unroll
      for (int nt = 0; nt < 8; ++nt) {
        const int h = hbase + nt * 16 + lrow;
        const float* ep = encb + (size_t)k0 * H + h;
        float b0 = ep[0 * H], b1 = ep[1 * H], b2 = ep[2 * H], b3 = ep[3 * H];
        float b4 = ep[4 * H], b5 = ep[5 * H], b6 = ep[6 * H], b7 = ep[7 * H];
        uint4 uu = make_uint4(pack_bf16(b0, b1), pack_bf16(b2, b3),
                              pack_bf16(b4, b5), pack_bf16(b6, b7));
        bf16x8 bfr = __builtin_bit_cast(bf16x8, uu);
        acc[nt] = __builtin_amdgcn_mfma_f32_16x16x32_bf16(pa, bfr, acc[nt], 0, 0, 0);
      }
    }
    const int crow = (lane >> 4) * 4, ccol = lane & 15;
#pragma unroll
    for (int nt = 0; nt < 8; ++nt) {
      const int h = hbase + nt * 16 + ccol;
#pragma unroll
      for (int reg = 0; reg < 4; ++reg) {
        const int t = crow + reg;
        out[((size_t)b * T + tt * TT + t) * H + h] = acc[nt][reg];
      }
    }
  }
}

extern "C" void kernel_launch(void* const* d_in, const int* in_sizes, int n_in,
                              void* d_out, int out_size, void* d_ws, size_t ws_size,
                              hipStream_t stream) {
  const float* query = (const float*)d_in[0];  // [B,T,H]
  const float* enc   = (const float*)d_in[1];  // [B,S,H]
  const int*   lens  = (const int*)d_in[2];    // [B]
  const float* Ws    = (const float*)d_in[3];  // [H,H]
  const float* Wh    = (const float*)d_in[4];  // [H,H]
  const float* v     = (const float*)d_in[5];  // [H]
  float* out = (float*)d_out;
  float* wsq  = (float*)d_ws;                  // Q4 [B,T/4,H/4,4,4]
  float* wheT = wsq + (size_t)B * T * H;       // E4 [B,H/4,S,4]

  mfma_matmul_kernel<<<dim3(QBLK + EBLK), 256, 0, stream>>>(query, enc, Ws, Wh, wsq, wheT, lens);
  attn_fused_kernel<<<dim3(B * (T / TT)), 256, 0, stream>>>(wsq, wheT, enc, v, lens, out);
}